// Round 1
// baseline (610.016 us; speedup 1.0000x reference)
//
#include <hip/hip_runtime.h>
#include <hip/hip_bf16.h>

// LinformerSelfAttention  B=4 N=4096 E=1024 H=16 D=64 K=256 RANK=32
// f32 I/O. All matmuls on MFMA with split-bf16 (hi/lo) operands.
// R6: chunked low-LDS fused attention + global_load_lds GEMM staging.
// R7: attn_fused P-staging is wave-private -> removed both per-chunk
//     __syncthreads() (they forced vmcnt(0) drains + 4-wave lockstep).

typedef unsigned short u16;
typedef __attribute__((ext_vector_type(8))) short bf8;          // 8 bf16 (4 VGPR)
typedef __attribute__((ext_vector_type(4))) float f32x4;
typedef __attribute__((ext_vector_type(8))) unsigned short us8;
typedef __attribute__((ext_vector_type(4))) unsigned short us4;

__device__ __forceinline__ u16 f2bf(float x) {
    __hip_bfloat16 h = __float2bfloat16(x);
    return *reinterpret_cast<u16*>(&h);
}
__device__ __forceinline__ float bf2f16(u16 u) {
    union { unsigned int i; float f; } c; c.i = ((unsigned int)u) << 16; return c.f;
}
__device__ __forceinline__ void async16(const void* g, void* l) {
    __builtin_amdgcn_global_load_lds(
        (const __attribute__((address_space(1))) void*)g,
        (__attribute__((address_space(3))) void*)l, 16, 0, 0);
}

// ---------------- weight splitter: f32 -> (hi bf16, lo bf16) ----------------
__global__ __launch_bounds__(256)
void split_w(const float* __restrict__ src, u16* __restrict__ h,
             u16* __restrict__ l, int n4) {
    int i = blockIdx.x * 256 + threadIdx.x;
    if (i >= n4) return;
    float4 v = ((const float4*)src)[i];
    float a[4] = {v.x, v.y, v.z, v.w};
    u16 hh[4], ll[4];
#pragma unroll
    for (int e = 0; e < 4; ++e) { u16 x = f2bf(a[e]); hh[e] = x; ll[e] = f2bf(a[e] - bf2f16(x)); }
    ((us4*)h)[i] = *(const us4*)hh;
    ((us4*)l)[i] = *(const us4*)ll;
}

// ---------------- pre-split GEMM, async LDS staging ----------------
// C[m,n] = sum_k A[m,k]*B[n,k] (+bias[n]).  BM=BN=128, BK=32.
// A,B pre-split u16. Staging via global_load_lds width=16 (m97 pattern).
template <bool HAS_BIAS, bool OUT_SPLIT>
__global__ __launch_bounds__(256)
void gemm_ps(const u16* __restrict__ Ah_g, const u16* __restrict__ Al_g,
             const u16* __restrict__ Bh_g, const u16* __restrict__ Bl_g,
             const float* __restrict__ bias,
             void* __restrict__ Ch_p, void* __restrict__ Cl_p,
             int M, int N, int K) {
    __shared__ u16 LAh[128 * 32], LAl[128 * 32], LBh[128 * 32], LBl[128 * 32];
    const int t = threadIdx.x;
    const int wave = t >> 6, lane = t & 63;
    const int l15 = lane & 15, quad = lane >> 4;
    const int wm = (wave >> 1) * 64, wn = (wave & 1) * 64;
    const int m0 = blockIdx.y * 128, n0 = blockIdx.x * 128;
    const int rl = lane >> 2, c4 = lane & 3;   // staging: row-in-16, 16B chunk

    f32x4 acc[4][4] = {};

    for (int k0 = 0; k0 < K; k0 += 32) {
#pragma unroll
        for (int j = 0; j < 2; ++j) {
            const int rloc = (wave * 2 + j) * 16 + rl;
            const size_t ga = (size_t)(m0 + rloc) * K + k0 + c4 * 8;
            const size_t gb = (size_t)(n0 + rloc) * K + k0 + c4 * 8;
            const int lo = (wave * 2 + j) * 512;   // u16 offset of this 1KB region
            async16(&Ah_g[ga], &LAh[lo]);
            async16(&Al_g[ga], &LAl[lo]);
            async16(&Bh_g[gb], &LBh[lo]);
            async16(&Bl_g[gb], &LBl[lo]);
        }
        __syncthreads();

        bf8 ah[4], al[4], bh[4], bl[4];
#pragma unroll
        for (int i = 0; i < 4; ++i) {
            ah[i] = *(const bf8*)&LAh[(wm + i * 16 + l15) * 32 + quad * 8];
            al[i] = *(const bf8*)&LAl[(wm + i * 16 + l15) * 32 + quad * 8];
            bh[i] = *(const bf8*)&LBh[(wn + i * 16 + l15) * 32 + quad * 8];
            bl[i] = *(const bf8*)&LBl[(wn + i * 16 + l15) * 32 + quad * 8];
        }
#pragma unroll
        for (int i = 0; i < 4; ++i)
#pragma unroll
            for (int j = 0; j < 4; ++j) {
                acc[i][j] = __builtin_amdgcn_mfma_f32_16x16x32_bf16(ah[i], bh[j], acc[i][j], 0, 0, 0);
                acc[i][j] = __builtin_amdgcn_mfma_f32_16x16x32_bf16(ah[i], bl[j], acc[i][j], 0, 0, 0);
                acc[i][j] = __builtin_amdgcn_mfma_f32_16x16x32_bf16(al[i], bh[j], acc[i][j], 0, 0, 0);
            }
        __syncthreads();
    }

    // C/D layout: col = lane&15 (B row), row = quad*4 + reg (A row)
#pragma unroll
    for (int j = 0; j < 4; ++j) {
        const int col = n0 + wn + j * 16 + l15;
        const float badd = HAS_BIAS ? bias[col] : 0.f;
#pragma unroll
        for (int i = 0; i < 4; ++i) {
            const int rbase = m0 + wm + i * 16 + quad * 4;
#pragma unroll
            for (int r = 0; r < 4; ++r) {
                float v = acc[i][j][r] + badd;
                size_t idx = (size_t)(rbase + r) * N + col;
                if (OUT_SPLIT) {
                    u16 hh = f2bf(v);
                    ((u16*)Ch_p)[idx] = hh;
                    ((u16*)Cl_p)[idx] = f2bf(v - bf2f16(hh));
                } else {
                    ((float*)Ch_p)[idx] = v;
                }
            }
        }
    }
}

// ---------------- f32-A GEMM (steps 1,4: A = x, small N) ----------------
template <int BN, bool OUT_SPLIT>
__global__ __launch_bounds__(256)
void gemm_xa(const float* __restrict__ A,
             const u16* __restrict__ Bh_g, const u16* __restrict__ Bl_g,
             void* __restrict__ Ch_p, void* __restrict__ Cl_p,
             int M, int N, int K) {
    constexpr int MI = (BN == 128) ? 4 : 2;
    constexpr int NJ = (BN == 32) ? 2 : 4;
    __shared__ u16 Ah[128][40], Al[128][40], Bh[BN][40], Bl[BN][40];
    const int t = threadIdx.x;
    const int wave = t >> 6, lane = t & 63;
    const int l15 = lane & 15, quad = lane >> 4;
    const int wm = (BN == 128) ? (wave >> 1) * 64 : wave * 32;
    const int wn = (BN == 128) ? (wave & 1) * 64 : 0;
    const int m0 = blockIdx.y * 128, n0 = blockIdx.x * BN;
    const int arow = t >> 1, acol = (t & 1) * 16;

    f32x4 acc[MI][NJ] = {};

    for (int k0 = 0; k0 < K; k0 += 32) {
        {
            const float* src = &A[(size_t)(m0 + arow) * K + k0 + acol];
            float4 w0 = ((const float4*)src)[0], w1 = ((const float4*)src)[1];
            float4 w2 = ((const float4*)src)[2], w3 = ((const float4*)src)[3];
            float v[16] = {w0.x, w0.y, w0.z, w0.w, w1.x, w1.y, w1.z, w1.w,
                           w2.x, w2.y, w2.z, w2.w, w3.x, w3.y, w3.z, w3.w};
            u16 hh[16], ll[16];
#pragma unroll
            for (int e = 0; e < 16; ++e) {
                u16 x = f2bf(v[e]); hh[e] = x; ll[e] = f2bf(v[e] - bf2f16(x));
            }
            *(us8*)&Ah[arow][acol]     = *(const us8*)&hh[0];
            *(us8*)&Ah[arow][acol + 8] = *(const us8*)&hh[8];
            *(us8*)&Al[arow][acol]     = *(const us8*)&ll[0];
            *(us8*)&Al[arow][acol + 8] = *(const us8*)&ll[8];
        }
        if (t < BN * 2) {
            const int brow = t >> 1, bcol = (t & 1) * 16;
            size_t base = (size_t)(n0 + brow) * K + k0 + bcol;
            *(us8*)&Bh[brow][bcol]     = *(const us8*)&Bh_g[base];
            *(us8*)&Bh[brow][bcol + 8] = *(const us8*)&Bh_g[base + 8];
            *(us8*)&Bl[brow][bcol]     = *(const us8*)&Bl_g[base];
            *(us8*)&Bl[brow][bcol + 8] = *(const us8*)&Bl_g[base + 8];
        }
        __syncthreads();

        bf8 ah[MI], al[MI], bh[NJ], bl[NJ];
#pragma unroll
        for (int i = 0; i < MI; ++i) {
            ah[i] = *(const bf8*)&Ah[wm + i * 16 + l15][quad * 8];
            al[i] = *(const bf8*)&Al[wm + i * 16 + l15][quad * 8];
        }
#pragma unroll
        for (int j = 0; j < NJ; ++j) {
            bh[j] = *(const bf8*)&Bh[wn + j * 16 + l15][quad * 8];
            bl[j] = *(const bf8*)&Bl[wn + j * 16 + l15][quad * 8];
        }
#pragma unroll
        for (int i = 0; i < MI; ++i)
#pragma unroll
            for (int j = 0; j < NJ; ++j) {
                acc[i][j] = __builtin_amdgcn_mfma_f32_16x16x32_bf16(ah[i], bh[j], acc[i][j], 0, 0, 0);
                acc[i][j] = __builtin_amdgcn_mfma_f32_16x16x32_bf16(ah[i], bl[j], acc[i][j], 0, 0, 0);
                acc[i][j] = __builtin_amdgcn_mfma_f32_16x16x32_bf16(al[i], bh[j], acc[i][j], 0, 0, 0);
            }
        __syncthreads();
    }

#pragma unroll
    for (int j = 0; j < NJ; ++j) {
        const int col = n0 + wn + j * 16 + l15;
#pragma unroll
        for (int i = 0; i < MI; ++i) {
            const int rbase = m0 + wm + i * 16 + quad * 4;
#pragma unroll
            for (int r = 0; r < 4; ++r) {
                float v = acc[i][j][r];
                size_t idx = (size_t)(rbase + r) * N + col;
                if (OUT_SPLIT) {
                    u16 hh = f2bf(v);
                    ((u16*)Ch_p)[idx] = hh;
                    ((u16*)Cl_p)[idx] = f2bf(v - bf2f16(hh));
                } else {
                    ((float*)Ch_p)[idx] = v;
                }
            }
        }
    }
}

// ---------------- kv: partial over n-segments ----------------
__global__ __launch_bounds__(256)
void kv_partial(const float* __restrict__ kmat, const float* __restrict__ kp,
                float* __restrict__ part) {
    const int b = blockIdx.y;
    const int seg = blockIdx.z;
    const int kk0 = blockIdx.x * 16;
    const int tid = threadIdx.x;
    const int d = tid & 63, s = tid >> 6;

    float acc[16] = {};
    const int nbeg = seg * 512;
    for (int n = nbeg + s; n < nbeg + 512; n += 4) {
        const float kval = kmat[((size_t)b * 4096 + n) * 64 + d];
        const float* kpr = &kp[(size_t)n * 256 + kk0];
#pragma unroll
        for (int j = 0; j < 16; ++j) acc[j] += kval * kpr[j];
    }
    __shared__ float sm[16][4][64];
#pragma unroll
    for (int j = 0; j < 16; ++j) sm[j][s][d] = acc[j];
    __syncthreads();
    for (int o = tid; o < 16 * 64; o += 256) {
        const int j = o >> 6, dd = o & 63;
        part[(((size_t)seg * 4 + b) * 256 + kk0 + j) * 64 + dd] =
            sm[j][0][dd] + sm[j][1][dd] + sm[j][2][dd] + sm[j][3][dd];
    }
}

// reduce 8 segments; emit pre-split KV ([b][k][d]) and KV^T ([b][d][k])
__global__ __launch_bounds__(256)
void kv_reduce_split(const float* __restrict__ part,
                     u16* __restrict__ kvh, u16* __restrict__ kvl,
                     u16* __restrict__ kvTh, u16* __restrict__ kvTl) {
    const int i = blockIdx.x * 256 + threadIdx.x;  // 0..65535
    float s = 0.f;
#pragma unroll
    for (int seg = 0; seg < 8; ++seg) s += part[(size_t)seg * 65536 + i];
    u16 hh = f2bf(s), ll = f2bf(s - bf2f16(hh));
    kvh[i] = hh;  kvl[i] = ll;
    const int b = i >> 14, k = (i >> 6) & 255, d = i & 63;
    size_t ti = ((size_t)b * 64 + d) * 256 + k;
    kvTh[ti] = hh;  kvTl[ti] = ll;
}

// ---------------- fused attention v3: chunked, low-LDS, BARRIER-FREE ----
// Block: 128 queries x one (b,h); 4 waves x 32 queries. 4 chunks of 64 keys.
// P staging in LDS is wave-private (each wave writes and reads only rows
// nwav..nwav+31), and DS ops complete in-order within a wave, so no
// __syncthreads() is needed anywhere: waves slip freely, and the compiler
// can pipeline chunk k+1's K/kvT loads under chunk k's MFMA/exp (the old
// barriers forced a vmcnt(0) drain 8x per block).
__global__ __launch_bounds__(256)
void attn_fused(const u16* __restrict__ qh, const u16* __restrict__ ql,
                const u16* __restrict__ kvh, const u16* __restrict__ kvl,
                const u16* __restrict__ kvTh, const u16* __restrict__ kvTl,
                u16* __restrict__ ath, u16* __restrict__ atl) {
    __shared__ u16 Ps[128][72];    // chunk of P[n_rel][k_loc], stride 72 u16
    const int b = blockIdx.z, h = blockIdx.y;
    const int t = threadIdx.x, wave = t >> 6, lane = t & 63;
    const int l15 = lane & 15, quad = lane >> 4;
    const int nblk = blockIdx.x * 128;
    const int nwav = wave * 32;

    // Q fragments (pre-split, direct from global)
    bf8 Qh[2][2], Ql[2][2];
#pragma unroll
    for (int nt = 0; nt < 2; ++nt) {
        size_t qoff = ((size_t)(b * 4096 + nblk + nwav + nt * 16 + l15)) * 1024
                      + h * 64 + quad * 8;
#pragma unroll
        for (int c = 0; c < 2; ++c) {
            Qh[nt][c] = *(const bf8*)&qh[qoff + c * 32];
            Ql[nt][c] = *(const bf8*)&ql[qoff + c * 32];
        }
    }

    f32x4 O[2][4] = {};
    float rsum[2] = {0.f, 0.f};

    for (int kc = 0; kc < 4; ++kc) {
        // ---- scores for this 64-key chunk
        f32x4 S[2][4] = {};
#pragma unroll
        for (int ktl = 0; ktl < 4; ++ktl) {
            const int krow = kc * 64 + ktl * 16 + l15;
            size_t koff = (size_t)b * 16384 + (size_t)krow * 64 + quad * 8;
#pragma unroll
            for (int c = 0; c < 2; ++c) {
                bf8 Kh = *(const bf8*)&kvh[koff + c * 32];
                bf8 Kl = *(const bf8*)&kvl[koff + c * 32];
#pragma unroll
                for (int nt = 0; nt < 2; ++nt) {
                    S[nt][ktl] = __builtin_amdgcn_mfma_f32_16x16x32_bf16(Kh, Qh[nt][c], S[nt][ktl], 0, 0, 0);
                    S[nt][ktl] = __builtin_amdgcn_mfma_f32_16x16x32_bf16(Kh, Ql[nt][c], S[nt][ktl], 0, 0, 0);
                    S[nt][ktl] = __builtin_amdgcn_mfma_f32_16x16x32_bf16(Kl, Qh[nt][c], S[nt][ktl], 0, 0, 0);
                }
            }
        }
        // ---- exp (no max-sub; s is O(1)), unnormalized bf16 P to LDS
        // (wave-private rows: no barrier needed before/after)
#pragma unroll
        for (int nt = 0; nt < 2; ++nt) {
            const int nrel = nwav + nt * 16 + l15;
#pragma unroll
            for (int ktl = 0; ktl < 4; ++ktl) {
                u16 pw[4];
#pragma unroll
                for (int r = 0; r < 4; ++r) {
                    float p = __expf(S[nt][ktl][r] * 0.125f);
                    rsum[nt] += p;
                    pw[r] = f2bf(p);
                }
                *(us4*)&Ps[nrel][ktl * 16 + quad * 4] = *(const us4*)pw;
            }
        }

        // ---- PV for this chunk
#pragma unroll
        for (int c = 0; c < 2; ++c) {
            bf8 pf[2];
#pragma unroll
            for (int nt = 0; nt < 2; ++nt) {
                const int nrel = nwav + nt * 16 + l15;
                pf[nt] = *(const bf8*)&Ps[nrel][c * 32 + quad * 8];
            }
#pragma unroll
            for (int dt = 0; dt < 4; ++dt) {
                const int drow = dt * 16 + l15;
                size_t toff = (size_t)b * 16384 + (size_t)drow * 256
                              + kc * 64 + c * 32 + quad * 8;
                bf8 th = *(const bf8*)&kvTh[toff];
                bf8 tl = *(const bf8*)&kvTl[toff];
#pragma unroll
                for (int nt = 0; nt < 2; ++nt) {
                    O[nt][dt] = __builtin_amdgcn_mfma_f32_16x16x32_bf16(pf[nt], th, O[nt][dt], 0, 0, 0);
                    O[nt][dt] = __builtin_amdgcn_mfma_f32_16x16x32_bf16(pf[nt], tl, O[nt][dt], 0, 0, 0);
                }
            }
        }
    }

    // full softmax denominators (per query n = nwav+nt*16+l15)
    float inv[2];
#pragma unroll
    for (int nt = 0; nt < 2; ++nt) {
        float s = rsum[nt];
        s += __shfl_xor(s, 16, 64);
        s += __shfl_xor(s, 32, 64);
        inv[nt] = 1.f / s;
    }

    // C: col = l15 -> d, row = quad*4+r -> query. Fetch that query's inv via
    // shfl(width=16): source lane has l15 == quad*4+r, same quad group.
#pragma unroll
    for (int nt = 0; nt < 2; ++nt)
#pragma unroll
        for (int dt = 0; dt < 4; ++dt) {
            const int dcol = dt * 16 + l15;
#pragma unroll
            for (int r = 0; r < 4; ++r) {
                const float qinv = __shfl(inv[nt], quad * 4 + r, 16);
                const int query = nblk + nwav + nt * 16 + quad * 4 + r;
                float v = O[nt][dt][r] * qinv;
                size_t idx = (size_t)(b * 4096 + query) * 1024 + h * 64 + dcol;
                u16 hh = f2bf(v);
                ath[idx] = hh;
                atl[idx] = f2bf(v - bf2f16(hh));
            }
        }
}

extern "C" void kernel_launch(void* const* d_in, const int* in_sizes, int n_in,
                              void* d_out, int out_size, void* d_ws, size_t ws_size,
                              hipStream_t stream) {
    const float* x  = (const float*)d_in[0];
    const float* qU = (const float*)d_in[1];
    const float* qV = (const float*)d_in[2];
    const float* qW = (const float*)d_in[3];
    const float* qb = (const float*)d_in[4];
    const float* kW = (const float*)d_in[5];
    const float* kp = (const float*)d_in[6];
    const float* oW = (const float*)d_in[7];
    const float* ob = (const float*)d_in[8];
    float* out = (float*)d_out;

    const int M = 16384;
    u16* W = (u16*)d_ws;
    u16* qUh = W;  W += 32768;    u16* qUl = W;  W += 32768;
    u16* qVh = W;  W += 16384;    u16* qVl = W;  W += 16384;
    u16* qWh = W;  W += 524288;   u16* qWl = W;  W += 524288;
    u16* kWh = W;  W += 65536;    u16* kWl = W;  W += 65536;
    u16* oWh = W;  W += 1048576;  u16* oWl = W;  W += 1048576;
    u16* t1h = W;  W += 524288;   u16* t1l = W;  W += 524288;
    u16* t2h = W;  W += 8388608;  u16* t2l = W;  W += 8388608;
    u16* qhb = W;  W += 16777216; u16* qlb = W;  W += 16777216;
    float* km  = (float*)W;  W += 2097152;     // 1048576 f32 (4 MB)
    u16* kvh  = W;  W += 65536;
    u16* kvl  = W;  W += 65536;
    u16* kvTh = W;  W += 65536;
    u16* kvTl = W;  W += 65536;
    u16* ath = qhb;                            // in-place over q buffers
    u16* atl = qlb;
    float* part = (float*)t1h;                 // 2 MB; t1 dead after step 2

    const dim3 blk(256);
    // 0) split weights
    split_w<<<dim3(32),   blk, 0, stream>>>(qU, qUh, qUl, 8192);
    split_w<<<dim3(16),   blk, 0, stream>>>(qV, qVh, qVl, 4096);
    split_w<<<dim3(512),  blk, 0, stream>>>(qW, qWh, qWl, 131072);
    split_w<<<dim3(64),   blk, 0, stream>>>(kW, kWh, kWl, 16384);
    split_w<<<dim3(1024), blk, 0, stream>>>(oW, oWh, oWl, 262144);
    // 1) t1 = x @ qU^T            (N=32, K=1024), out pre-split
    gemm_xa<32, true><<<dim3(1, 128), blk, 0, stream>>>(
        x, qUh, qUl, t1h, t1l, M, 32, 1024);
    // 2) t2 = t1 @ qV^T           (N=512, K=32), out pre-split
    gemm_ps<false, true><<<dim3(4, 128), blk, 0, stream>>>(
        t1h, t1l, qVh, qVl, nullptr, t2h, t2l, M, 512, 32);
    // 3) q = t2 @ qW^T + qb       (N=1024, K=512), out pre-split
    gemm_ps<true, true><<<dim3(8, 128), blk, 0, stream>>>(
        t2h, t2l, qWh, qWl, qb, qhb, qlb, M, 1024, 512);
    // 4) km = x @ kW^T            (N=64, K=1024), f32 out
    gemm_xa<64, false><<<dim3(1, 128), blk, 0, stream>>>(
        x, kWh, kWl, km, nullptr, M, 64, 1024);
    // 5) kv partial + reduce/split (+ transpose)
    kv_partial<<<dim3(16, 4, 8), blk, 0, stream>>>(km, kp, part);
    kv_reduce_split<<<dim3(256), blk, 0, stream>>>(part, kvh, kvl, kvTh, kvTl);
    // 6) fused attention (in-place over q buffers)
    attn_fused<<<dim3(32, 16, 4), blk, 0, stream>>>(qhb, qlb, kvh, kvl, kvTh, kvTl, ath, atl);
    // 7) out = at @ oW^T + ob     (N=1024, K=1024), f32 out
    gemm_ps<true, false><<<dim3(8, 128), blk, 0, stream>>>(
        ath, atl, oWh, oWl, ob, out, nullptr, M, 1024, 1024);
}

// Round 2
// 520.152 us; speedup vs baseline: 1.1728x; 1.1728x over previous
//
#include <hip/hip_runtime.h>
#include <hip/hip_bf16.h>

// LinformerSelfAttention  B=4 N=4096 E=1024 H=16 D=64 K=256 RANK=32
// f32 I/O. All matmuls on MFMA with split-bf16 (hi/lo) operands.
// R6: chunked low-LDS fused attention + global_load_lds GEMM staging.
// R7: removed attn barriers -> NEUTRAL (barriers proven free).
// R8: attn KV chunks cooperatively staged in LDS (4x fewer global reads;
//     the 4 waves of a block were re-reading identical lines, and all
//     resident waves chip-wide hammered the same 512KB of L2 lines).
//     P buffer shrunk to [128][64] + XOR swizzle to keep 3 blocks/CU.

typedef unsigned short u16;
typedef __attribute__((ext_vector_type(8))) short bf8;          // 8 bf16 (4 VGPR)
typedef __attribute__((ext_vector_type(4))) float f32x4;
typedef __attribute__((ext_vector_type(8))) unsigned short us8;
typedef __attribute__((ext_vector_type(4))) unsigned short us4;

__device__ __forceinline__ u16 f2bf(float x) {
    __hip_bfloat16 h = __float2bfloat16(x);
    return *reinterpret_cast<u16*>(&h);
}
__device__ __forceinline__ float bf2f16(u16 u) {
    union { unsigned int i; float f; } c; c.i = ((unsigned int)u) << 16; return c.f;
}
__device__ __forceinline__ void async16(const void* g, void* l) {
    __builtin_amdgcn_global_load_lds(
        (const __attribute__((address_space(1))) void*)g,
        (__attribute__((address_space(3))) void*)l, 16, 0, 0);
}

// ---------------- weight splitter: f32 -> (hi bf16, lo bf16) ----------------
__global__ __launch_bounds__(256)
void split_w(const float* __restrict__ src, u16* __restrict__ h,
             u16* __restrict__ l, int n4) {
    int i = blockIdx.x * 256 + threadIdx.x;
    if (i >= n4) return;
    float4 v = ((const float4*)src)[i];
    float a[4] = {v.x, v.y, v.z, v.w};
    u16 hh[4], ll[4];
#pragma unroll
    for (int e = 0; e < 4; ++e) { u16 x = f2bf(a[e]); hh[e] = x; ll[e] = f2bf(a[e] - bf2f16(x)); }
    ((us4*)h)[i] = *(const us4*)hh;
    ((us4*)l)[i] = *(const us4*)ll;
}

// ---------------- pre-split GEMM, async LDS staging ----------------
// C[m,n] = sum_k A[m,k]*B[n,k] (+bias[n]).  BM=BN=128, BK=32.
// A,B pre-split u16. Staging via global_load_lds width=16 (m97 pattern).
template <bool HAS_BIAS, bool OUT_SPLIT>
__global__ __launch_bounds__(256)
void gemm_ps(const u16* __restrict__ Ah_g, const u16* __restrict__ Al_g,
             const u16* __restrict__ Bh_g, const u16* __restrict__ Bl_g,
             const float* __restrict__ bias,
             void* __restrict__ Ch_p, void* __restrict__ Cl_p,
             int M, int N, int K) {
    __shared__ u16 LAh[128 * 32], LAl[128 * 32], LBh[128 * 32], LBl[128 * 32];
    const int t = threadIdx.x;
    const int wave = t >> 6, lane = t & 63;
    const int l15 = lane & 15, quad = lane >> 4;
    const int wm = (wave >> 1) * 64, wn = (wave & 1) * 64;
    const int m0 = blockIdx.y * 128, n0 = blockIdx.x * 128;
    const int rl = lane >> 2, c4 = lane & 3;   // staging: row-in-16, 16B chunk

    f32x4 acc[4][4] = {};

    for (int k0 = 0; k0 < K; k0 += 32) {
#pragma unroll
        for (int j = 0; j < 2; ++j) {
            const int rloc = (wave * 2 + j) * 16 + rl;
            const size_t ga = (size_t)(m0 + rloc) * K + k0 + c4 * 8;
            const size_t gb = (size_t)(n0 + rloc) * K + k0 + c4 * 8;
            const int lo = (wave * 2 + j) * 512;   // u16 offset of this 1KB region
            async16(&Ah_g[ga], &LAh[lo]);
            async16(&Al_g[ga], &LAl[lo]);
            async16(&Bh_g[gb], &LBh[lo]);
            async16(&Bl_g[gb], &LBl[lo]);
        }
        __syncthreads();

        bf8 ah[4], al[4], bh[4], bl[4];
#pragma unroll
        for (int i = 0; i < 4; ++i) {
            ah[i] = *(const bf8*)&LAh[(wm + i * 16 + l15) * 32 + quad * 8];
            al[i] = *(const bf8*)&LAl[(wm + i * 16 + l15) * 32 + quad * 8];
            bh[i] = *(const bf8*)&LBh[(wn + i * 16 + l15) * 32 + quad * 8];
            bl[i] = *(const bf8*)&LBl[(wn + i * 16 + l15) * 32 + quad * 8];
        }
#pragma unroll
        for (int i = 0; i < 4; ++i)
#pragma unroll
            for (int j = 0; j < 4; ++j) {
                acc[i][j] = __builtin_amdgcn_mfma_f32_16x16x32_bf16(ah[i], bh[j], acc[i][j], 0, 0, 0);
                acc[i][j] = __builtin_amdgcn_mfma_f32_16x16x32_bf16(ah[i], bl[j], acc[i][j], 0, 0, 0);
                acc[i][j] = __builtin_amdgcn_mfma_f32_16x16x32_bf16(al[i], bh[j], acc[i][j], 0, 0, 0);
            }
        __syncthreads();
    }

    // C/D layout: col = lane&15 (B row), row = quad*4 + reg (A row)
#pragma unroll
    for (int j = 0; j < 4; ++j) {
        const int col = n0 + wn + j * 16 + l15;
        const float badd = HAS_BIAS ? bias[col] : 0.f;
#pragma unroll
        for (int i = 0; i < 4; ++i) {
            const int rbase = m0 + wm + i * 16 + quad * 4;
#pragma unroll
            for (int r = 0; r < 4; ++r) {
                float v = acc[i][j][r] + badd;
                size_t idx = (size_t)(rbase + r) * N + col;
                if (OUT_SPLIT) {
                    u16 hh = f2bf(v);
                    ((u16*)Ch_p)[idx] = hh;
                    ((u16*)Cl_p)[idx] = f2bf(v - bf2f16(hh));
                } else {
                    ((float*)Ch_p)[idx] = v;
                }
            }
        }
    }
}

// ---------------- f32-A GEMM (steps 1,4: A = x, small N) ----------------
template <int BN, bool OUT_SPLIT>
__global__ __launch_bounds__(256)
void gemm_xa(const float* __restrict__ A,
             const u16* __restrict__ Bh_g, const u16* __restrict__ Bl_g,
             void* __restrict__ Ch_p, void* __restrict__ Cl_p,
             int M, int N, int K) {
    constexpr int MI = (BN == 128) ? 4 : 2;
    constexpr int NJ = (BN == 32) ? 2 : 4;
    __shared__ u16 Ah[128][40], Al[128][40], Bh[BN][40], Bl[BN][40];
    const int t = threadIdx.x;
    const int wave = t >> 6, lane = t & 63;
    const int l15 = lane & 15, quad = lane >> 4;
    const int wm = (BN == 128) ? (wave >> 1) * 64 : wave * 32;
    const int wn = (BN == 128) ? (wave & 1) * 64 : 0;
    const int m0 = blockIdx.y * 128, n0 = blockIdx.x * BN;
    const int arow = t >> 1, acol = (t & 1) * 16;

    f32x4 acc[MI][NJ] = {};

    for (int k0 = 0; k0 < K; k0 += 32) {
        {
            const float* src = &A[(size_t)(m0 + arow) * K + k0 + acol];
            float4 w0 = ((const float4*)src)[0], w1 = ((const float4*)src)[1];
            float4 w2 = ((const float4*)src)[2], w3 = ((const float4*)src)[3];
            float v[16] = {w0.x, w0.y, w0.z, w0.w, w1.x, w1.y, w1.z, w1.w,
                           w2.x, w2.y, w2.z, w2.w, w3.x, w3.y, w3.z, w3.w};
            u16 hh[16], ll[16];
#pragma unroll
            for (int e = 0; e < 16; ++e) {
                u16 x = f2bf(v[e]); hh[e] = x; ll[e] = f2bf(v[e] - bf2f16(x));
            }
            *(us8*)&Ah[arow][acol]     = *(const us8*)&hh[0];
            *(us8*)&Ah[arow][acol + 8] = *(const us8*)&hh[8];
            *(us8*)&Al[arow][acol]     = *(const us8*)&ll[0];
            *(us8*)&Al[arow][acol + 8] = *(const us8*)&ll[8];
        }
        if (t < BN * 2) {
            const int brow = t >> 1, bcol = (t & 1) * 16;
            size_t base = (size_t)(n0 + brow) * K + k0 + bcol;
            *(us8*)&Bh[brow][bcol]     = *(const us8*)&Bh_g[base];
            *(us8*)&Bh[brow][bcol + 8] = *(const us8*)&Bh_g[base + 8];
            *(us8*)&Bl[brow][bcol]     = *(const us8*)&Bl_g[base];
            *(us8*)&Bl[brow][bcol + 8] = *(const us8*)&Bl_g[base + 8];
        }
        __syncthreads();

        bf8 ah[MI], al[MI], bh[NJ], bl[NJ];
#pragma unroll
        for (int i = 0; i < MI; ++i) {
            ah[i] = *(const bf8*)&Ah[wm + i * 16 + l15][quad * 8];
            al[i] = *(const bf8*)&Al[wm + i * 16 + l15][quad * 8];
        }
#pragma unroll
        for (int j = 0; j < NJ; ++j) {
            bh[j] = *(const bf8*)&Bh[wn + j * 16 + l15][quad * 8];
            bl[j] = *(const bf8*)&Bl[wn + j * 16 + l15][quad * 8];
        }
#pragma unroll
        for (int i = 0; i < MI; ++i)
#pragma unroll
            for (int j = 0; j < NJ; ++j) {
                acc[i][j] = __builtin_amdgcn_mfma_f32_16x16x32_bf16(ah[i], bh[j], acc[i][j], 0, 0, 0);
                acc[i][j] = __builtin_amdgcn_mfma_f32_16x16x32_bf16(ah[i], bl[j], acc[i][j], 0, 0, 0);
                acc[i][j] = __builtin_amdgcn_mfma_f32_16x16x32_bf16(al[i], bh[j], acc[i][j], 0, 0, 0);
            }
        __syncthreads();
    }

#pragma unroll
    for (int j = 0; j < NJ; ++j) {
        const int col = n0 + wn + j * 16 + l15;
#pragma unroll
        for (int i = 0; i < MI; ++i) {
            const int rbase = m0 + wm + i * 16 + quad * 4;
#pragma unroll
            for (int r = 0; r < 4; ++r) {
                float v = acc[i][j][r];
                size_t idx = (size_t)(rbase + r) * N + col;
                if (OUT_SPLIT) {
                    u16 hh = f2bf(v);
                    ((u16*)Ch_p)[idx] = hh;
                    ((u16*)Cl_p)[idx] = f2bf(v - bf2f16(hh));
                } else {
                    ((float*)Ch_p)[idx] = v;
                }
            }
        }
    }
}

// ---------------- kv: partial over n-segments ----------------
__global__ __launch_bounds__(256)
void kv_partial(const float* __restrict__ kmat, const float* __restrict__ kp,
                float* __restrict__ part) {
    const int b = blockIdx.y;
    const int seg = blockIdx.z;
    const int kk0 = blockIdx.x * 16;
    const int tid = threadIdx.x;
    const int d = tid & 63, s = tid >> 6;

    float acc[16] = {};
    const int nbeg = seg * 512;
    for (int n = nbeg + s; n < nbeg + 512; n += 4) {
        const float kval = kmat[((size_t)b * 4096 + n) * 64 + d];
        const float* kpr = &kp[(size_t)n * 256 + kk0];
#pragma unroll
        for (int j = 0; j < 16; ++j) acc[j] += kval * kpr[j];
    }
    __shared__ float sm[16][4][64];
#pragma unroll
    for (int j = 0; j < 16; ++j) sm[j][s][d] = acc[j];
    __syncthreads();
    for (int o = tid; o < 16 * 64; o += 256) {
        const int j = o >> 6, dd = o & 63;
        part[(((size_t)seg * 4 + b) * 256 + kk0 + j) * 64 + dd] =
            sm[j][0][dd] + sm[j][1][dd] + sm[j][2][dd] + sm[j][3][dd];
    }
}

// reduce 8 segments; emit pre-split KV ([b][k][d]) and KV^T ([b][d][k])
__global__ __launch_bounds__(256)
void kv_reduce_split(const float* __restrict__ part,
                     u16* __restrict__ kvh, u16* __restrict__ kvl,
                     u16* __restrict__ kvTh, u16* __restrict__ kvTl) {
    const int i = blockIdx.x * 256 + threadIdx.x;  // 0..65535
    float s = 0.f;
#pragma unroll
    for (int seg = 0; seg < 8; ++seg) s += part[(size_t)seg * 65536 + i];
    u16 hh = f2bf(s), ll = f2bf(s - bf2f16(hh));
    kvh[i] = hh;  kvl[i] = ll;
    const int b = i >> 14, k = (i >> 6) & 255, d = i & 63;
    size_t ti = ((size_t)b * 64 + d) * 256 + k;
    kvTh[ti] = hh;  kvTl[ti] = ll;
}

// ---------------- fused attention v4: LDS-staged KV chunks ----------------
// Block: 128 queries x one (b,h); 4 waves x 32 queries. 4 chunks of 64 keys.
// Per chunk: all 256 threads cooperatively stage K-chunk (hi+lo) and
// V^T-chunk (hi+lo) into padded LDS (reg-staged so leading dim = 72 is
// possible -> ~2-way bank conflicts only). This cuts global KV loads 4x
// per block (waves previously each re-read identical lines; chip-wide the
// same 512KB line set was hammered by ~3K waves -> L2 serialization).
// P buffer: [128][64] with XOR swizzle (byte ^= (row&7)<<4 on BOTH write
// and read) -> conflict-free and 2KB smaller, keeping LDS at 53248 B
// (3 blocks/CU together with ~136 unified VGPR+AGPR).
__global__ __launch_bounds__(256)
void attn_fused(const u16* __restrict__ qh, const u16* __restrict__ ql,
                const u16* __restrict__ kvh, const u16* __restrict__ kvl,
                const u16* __restrict__ kvTh, const u16* __restrict__ kvTl,
                u16* __restrict__ ath, u16* __restrict__ atl) {
    __shared__ u16 Kh_s[64][72], Kl_s[64][72];   // K chunk  [k_loc][d]
    __shared__ u16 Vh_s[64][72], Vl_s[64][72];   // V^T chunk [d][k_loc]
    __shared__ u16 Ps[128 * 64];                 // P chunk, XOR-swizzled
    const int b = blockIdx.z, h = blockIdx.y;
    const int t = threadIdx.x, wave = t >> 6, lane = t & 63;
    const int l15 = lane & 15, quad = lane >> 4;
    const int nblk = blockIdx.x * 128;
    const int nwav = wave * 32;
    char* Pb = (char*)Ps;

    // Q fragments (pre-split, direct from global)
    bf8 Qh[2][2], Ql[2][2];
#pragma unroll
    for (int nt = 0; nt < 2; ++nt) {
        size_t qoff = ((size_t)(b * 4096 + nblk + nwav + nt * 16 + l15)) * 1024
                      + h * 64 + quad * 8;
#pragma unroll
        for (int c = 0; c < 2; ++c) {
            Qh[nt][c] = *(const bf8*)&qh[qoff + c * 32];
            Ql[nt][c] = *(const bf8*)&ql[qoff + c * 32];
        }
    }

    f32x4 O[2][4] = {};
    float rsum[2] = {0.f, 0.f};

    const int srow = t >> 3;            // 0..31, staging row
    const int scol = (t & 7) * 8;       // u16 col (16B chunk)
    const size_t kb = (size_t)b * 16384;

    for (int kc = 0; kc < 4; ++kc) {
        // ---- cooperative stage: K chunk + V^T chunk (hi+lo) -> LDS
        {
            bf8 s0 = *(const bf8*)&kvh [kb + (size_t)(kc * 64 + srow     ) * 64 + scol];
            bf8 s1 = *(const bf8*)&kvh [kb + (size_t)(kc * 64 + srow + 32) * 64 + scol];
            bf8 s2 = *(const bf8*)&kvl [kb + (size_t)(kc * 64 + srow     ) * 64 + scol];
            bf8 s3 = *(const bf8*)&kvl [kb + (size_t)(kc * 64 + srow + 32) * 64 + scol];
            bf8 s4 = *(const bf8*)&kvTh[kb + (size_t)(srow     ) * 256 + kc * 64 + scol];
            bf8 s5 = *(const bf8*)&kvTh[kb + (size_t)(srow + 32) * 256 + kc * 64 + scol];
            bf8 s6 = *(const bf8*)&kvTl[kb + (size_t)(srow     ) * 256 + kc * 64 + scol];
            bf8 s7 = *(const bf8*)&kvTl[kb + (size_t)(srow + 32) * 256 + kc * 64 + scol];
            *(bf8*)&Kh_s[srow     ][scol] = s0;
            *(bf8*)&Kh_s[srow + 32][scol] = s1;
            *(bf8*)&Kl_s[srow     ][scol] = s2;
            *(bf8*)&Kl_s[srow + 32][scol] = s3;
            *(bf8*)&Vh_s[srow     ][scol] = s4;
            *(bf8*)&Vh_s[srow + 32][scol] = s5;
            *(bf8*)&Vl_s[srow     ][scol] = s6;
            *(bf8*)&Vl_s[srow + 32][scol] = s7;
        }
        __syncthreads();

        // ---- scores for this 64-key chunk (K from LDS)
        f32x4 S[2][4] = {};
#pragma unroll
        for (int ktl = 0; ktl < 4; ++ktl) {
            const int krl = ktl * 16 + l15;      // key row within chunk
#pragma unroll
            for (int c = 0; c < 2; ++c) {
                bf8 Kh = *(const bf8*)&Kh_s[krl][c * 32 + quad * 8];
                bf8 Kl = *(const bf8*)&Kl_s[krl][c * 32 + quad * 8];
#pragma unroll
                for (int nt = 0; nt < 2; ++nt) {
                    S[nt][ktl] = __builtin_amdgcn_mfma_f32_16x16x32_bf16(Kh, Qh[nt][c], S[nt][ktl], 0, 0, 0);
                    S[nt][ktl] = __builtin_amdgcn_mfma_f32_16x16x32_bf16(Kh, Ql[nt][c], S[nt][ktl], 0, 0, 0);
                    S[nt][ktl] = __builtin_amdgcn_mfma_f32_16x16x32_bf16(Kl, Qh[nt][c], S[nt][ktl], 0, 0, 0);
                }
            }
        }
        // ---- exp (no max-sub; s is O(1)), unnormalized bf16 P to LDS
        // (wave-private rows; swizzled byte addressing, same XOR both sides)
#pragma unroll
        for (int nt = 0; nt < 2; ++nt) {
            const int nrel = nwav + nt * 16 + l15;
#pragma unroll
            for (int ktl = 0; ktl < 4; ++ktl) {
                u16 pw[4];
#pragma unroll
                for (int r = 0; r < 4; ++r) {
                    float p = __expf(S[nt][ktl][r] * 0.125f);
                    rsum[nt] += p;
                    pw[r] = f2bf(p);
                }
                *(us4*)(Pb + ((nrel * 128 + ktl * 32 + quad * 8) ^ ((nrel & 7) << 4)))
                    = *(const us4*)pw;
            }
        }

        // ---- PV for this chunk (V^T from LDS)
#pragma unroll
        for (int c = 0; c < 2; ++c) {
            bf8 pf[2];
#pragma unroll
            for (int nt = 0; nt < 2; ++nt) {
                const int nrel = nwav + nt * 16 + l15;
                pf[nt] = *(const bf8*)(Pb + ((nrel * 128 + c * 64 + quad * 16) ^ ((nrel & 7) << 4)));
            }
#pragma unroll
            for (int dt = 0; dt < 4; ++dt) {
                const int drow = dt * 16 + l15;
                bf8 th = *(const bf8*)&Vh_s[drow][c * 32 + quad * 8];
                bf8 tl = *(const bf8*)&Vl_s[drow][c * 32 + quad * 8];
#pragma unroll
                for (int nt = 0; nt < 2; ++nt) {
                    O[nt][dt] = __builtin_amdgcn_mfma_f32_16x16x32_bf16(pf[nt], th, O[nt][dt], 0, 0, 0);
                    O[nt][dt] = __builtin_amdgcn_mfma_f32_16x16x32_bf16(pf[nt], tl, O[nt][dt], 0, 0, 0);
                }
            }
        }
        __syncthreads();   // protect K/V LDS from next chunk's staging
    }

    // full softmax denominators (per query n = nwav+nt*16+l15)
    float inv[2];
#pragma unroll
    for (int nt = 0; nt < 2; ++nt) {
        float s = rsum[nt];
        s += __shfl_xor(s, 16, 64);
        s += __shfl_xor(s, 32, 64);
        inv[nt] = 1.f / s;
    }

    // C: col = l15 -> d, row = quad*4+r -> query. Fetch that query's inv via
    // shfl(width=16): source lane has l15 == quad*4+r, same quad group.
#pragma unroll
    for (int nt = 0; nt < 2; ++nt)
#pragma unroll
        for (int dt = 0; dt < 4; ++dt) {
            const int dcol = dt * 16 + l15;
#pragma unroll
            for (int r = 0; r < 4; ++r) {
                const float qinv = __shfl(inv[nt], quad * 4 + r, 16);
                const int query = nblk + nwav + nt * 16 + quad * 4 + r;
                float v = O[nt][dt][r] * qinv;
                size_t idx = (size_t)(b * 4096 + query) * 1024 + h * 64 + dcol;
                u16 hh = f2bf(v);
                ath[idx] = hh;
                atl[idx] = f2bf(v - bf2f16(hh));
            }
        }
}

extern "C" void kernel_launch(void* const* d_in, const int* in_sizes, int n_in,
                              void* d_out, int out_size, void* d_ws, size_t ws_size,
                              hipStream_t stream) {
    const float* x  = (const float*)d_in[0];
    const float* qU = (const float*)d_in[1];
    const float* qV = (const float*)d_in[2];
    const float* qW = (const float*)d_in[3];
    const float* qb = (const float*)d_in[4];
    const float* kW = (const float*)d_in[5];
    const float* kp = (const float*)d_in[6];
    const float* oW = (const float*)d_in[7];
    const float* ob = (const float*)d_in[8];
    float* out = (float*)d_out;

    const int M = 16384;
    u16* W = (u16*)d_ws;
    u16* qUh = W;  W += 32768;    u16* qUl = W;  W += 32768;
    u16* qVh = W;  W += 16384;    u16* qVl = W;  W += 16384;
    u16* qWh = W;  W += 524288;   u16* qWl = W;  W += 524288;
    u16* kWh = W;  W += 65536;    u16* kWl = W;  W += 65536;
    u16* oWh = W;  W += 1048576;  u16* oWl = W;  W += 1048576;
    u16* t1h = W;  W += 524288;   u16* t1l = W;  W += 524288;
    u16* t2h = W;  W += 8388608;  u16* t2l = W;  W += 8388608;
    u16* qhb = W;  W += 16777216; u16* qlb = W;  W += 16777216;
    float* km  = (float*)W;  W += 2097152;     // 1048576 f32 (4 MB)
    u16* kvh  = W;  W += 65536;
    u16* kvl  = W;  W += 65536;
    u16* kvTh = W;  W += 65536;
    u16* kvTl = W;  W += 65536;
    u16* ath = qhb;                            // in-place over q buffers
    u16* atl = qlb;
    float* part = (float*)t1h;                 // 2 MB; t1 dead after step 2

    const dim3 blk(256);
    // 0) split weights
    split_w<<<dim3(32),   blk, 0, stream>>>(qU, qUh, qUl, 8192);
    split_w<<<dim3(16),   blk, 0, stream>>>(qV, qVh, qVl, 4096);
    split_w<<<dim3(512),  blk, 0, stream>>>(qW, qWh, qWl, 131072);
    split_w<<<dim3(64),   blk, 0, stream>>>(kW, kWh, kWl, 16384);
    split_w<<<dim3(1024), blk, 0, stream>>>(oW, oWh, oWl, 262144);
    // 1) t1 = x @ qU^T            (N=32, K=1024), out pre-split
    gemm_xa<32, true><<<dim3(1, 128), blk, 0, stream>>>(
        x, qUh, qUl, t1h, t1l, M, 32, 1024);
    // 2) t2 = t1 @ qV^T           (N=512, K=32), out pre-split
    gemm_ps<false, true><<<dim3(4, 128), blk, 0, stream>>>(
        t1h, t1l, qVh, qVl, nullptr, t2h, t2l, M, 512, 32);
    // 3) q = t2 @ qW^T + qb       (N=1024, K=512), out pre-split
    gemm_ps<true, true><<<dim3(8, 128), blk, 0, stream>>>(
        t2h, t2l, qWh, qWl, qb, qhb, qlb, M, 1024, 512);
    // 4) km = x @ kW^T            (N=64, K=1024), f32 out
    gemm_xa<64, false><<<dim3(1, 128), blk, 0, stream>>>(
        x, kWh, kWl, km, nullptr, M, 64, 1024);
    // 5) kv partial + reduce/split (+ transpose)
    kv_partial<<<dim3(16, 4, 8), blk, 0, stream>>>(km, kp, part);
    kv_reduce_split<<<dim3(256), blk, 0, stream>>>(part, kvh, kvl, kvTh, kvTl);
    // 6) fused attention (in-place over q buffers)
    attn_fused<<<dim3(32, 16, 4), blk, 0, stream>>>(qhb, qlb, kvh, kvl, kvTh, kvTl, ath, atl);
    // 7) out = at @ oW^T + ob     (N=1024, K=1024), f32 out
    gemm_ps<true, false><<<dim3(8, 128), blk, 0, stream>>>(
        ath, atl, oWh, oWl, ob, out, nullptr, M, 1024, 1024);
}

// Round 3
// 377.055 us; speedup vs baseline: 1.6178x; 1.3795x over previous
//
#include <hip/hip_runtime.h>

// LinformerSelfAttention  B=4 N=4096 E=1024 H=16 D=64 K=256 RANK=32
// f32 I/O.
// R6: chunked low-LDS fused attention + global_load_lds GEMM staging.
// R7: removed attn barriers -> NEUTRAL (barriers proven free).
// R8: attn KV chunks staged in LDS -> -90us (L2 same-line hotspot fixed).
// R9: replaced split-bf16 (hi/lo, 3-MFMA) with SINGLE f16 operands
//     everywhere: 3x less MFMA, 2x less staged memory/LDS, and BETTER
//     precision (f16 2^-11 vs bf16 2^-8; old absmax was dominated by
//     bf16 P). exp shifted by -4 (cancels in softmax) to keep P in f16
//     range. + XCD-aware block swizzle in gemm_ps (A-panel was fetched
//     by 8 different XCD L2s -> 4x over-fetch).

typedef unsigned short u16;
typedef _Float16 f16;
typedef __attribute__((ext_vector_type(8))) _Float16 h8;        // 8 f16 (4 VGPR)
typedef __attribute__((ext_vector_type(4))) float f32x4;
typedef __attribute__((ext_vector_type(8))) unsigned short us8;
typedef __attribute__((ext_vector_type(4))) unsigned short us4;

__device__ __forceinline__ u16 f2h(float x) {
    f16 h = (f16)x;
    union { f16 hf; u16 u; } c; c.hf = h; return c.u;
}
__device__ __forceinline__ void async16(const void* g, void* l) {
    __builtin_amdgcn_global_load_lds(
        (const __attribute__((address_space(1))) void*)g,
        (__attribute__((address_space(3))) void*)l, 16, 0, 0);
}

// ---------------- weight converter: f32 -> f16 ----------------
__global__ __launch_bounds__(256)
void cvt_w(const float* __restrict__ src, u16* __restrict__ h, int n4) {
    int i = blockIdx.x * 256 + threadIdx.x;
    if (i >= n4) return;
    float4 v = ((const float4*)src)[i];
    u16 hh[4] = {f2h(v.x), f2h(v.y), f2h(v.z), f2h(v.w)};
    ((us4*)h)[i] = *(const us4*)hh;
}

// ---------------- f16 GEMM, async LDS staging ----------------
// C[m,n] = sum_k A[m,k]*B[n,k] (+bias[n]).  BM=BN=128, BK=32.
// A,B f16 (u16 bits). Staging via global_load_lds width=16 (m97 pattern).
// XCD-aware swizzle: requires gridDim.x*gridDim.y % 8 == 0.
template <bool HAS_BIAS, bool OUT_F16>
__global__ __launch_bounds__(256)
void gemm_ps(const u16* __restrict__ A_g, const u16* __restrict__ B_g,
             const float* __restrict__ bias, void* __restrict__ C_p,
             int M, int N, int K) {
    __shared__ u16 LA[128 * 32], LB[128 * 32];
    const int t = threadIdx.x;
    const int wave = t >> 6, lane = t & 63;
    const int l15 = lane & 15, quad = lane >> 4;
    const int wm = (wave >> 1) * 64, wn = (wave & 1) * 64;
    // XCD swizzle (dispatch id -> contiguous per-XCD chunk)
    const int gx = gridDim.x;
    const int nwg = gx * gridDim.y;
    const int flat = blockIdx.y * gx + blockIdx.x;
    const int cpx = nwg >> 3;
    const int swz = (flat & 7) * cpx + (flat >> 3);
    const int m0 = (swz / gx) * 128, n0 = (swz % gx) * 128;
    const int rl = lane >> 2, c4 = lane & 3;   // staging: row-in-16, 16B chunk

    f32x4 acc[4][4] = {};

    for (int k0 = 0; k0 < K; k0 += 32) {
#pragma unroll
        for (int j = 0; j < 2; ++j) {
            const int rloc = (wave * 2 + j) * 16 + rl;
            const size_t ga = (size_t)(m0 + rloc) * K + k0 + c4 * 8;
            const size_t gb = (size_t)(n0 + rloc) * K + k0 + c4 * 8;
            const int lo = (wave * 2 + j) * 512;   // u16 offset of this 1KB region
            async16(&A_g[ga], &LA[lo]);
            async16(&B_g[gb], &LB[lo]);
        }
        __syncthreads();

        h8 ah[4], bh[4];
#pragma unroll
        for (int i = 0; i < 4; ++i) {
            ah[i] = *(const h8*)&LA[(wm + i * 16 + l15) * 32 + quad * 8];
            bh[i] = *(const h8*)&LB[(wn + i * 16 + l15) * 32 + quad * 8];
        }
#pragma unroll
        for (int i = 0; i < 4; ++i)
#pragma unroll
            for (int j = 0; j < 4; ++j)
                acc[i][j] = __builtin_amdgcn_mfma_f32_16x16x32_f16(ah[i], bh[j], acc[i][j], 0, 0, 0);
        __syncthreads();
    }

    // C/D layout: col = lane&15 (B row), row = quad*4 + reg (A row)
#pragma unroll
    for (int j = 0; j < 4; ++j) {
        const int col = n0 + wn + j * 16 + l15;
        const float badd = HAS_BIAS ? bias[col] : 0.f;
#pragma unroll
        for (int i = 0; i < 4; ++i) {
            const int rbase = m0 + wm + i * 16 + quad * 4;
#pragma unroll
            for (int r = 0; r < 4; ++r) {
                float v = acc[i][j][r] + badd;
                size_t idx = (size_t)(rbase + r) * N + col;
                if (OUT_F16) ((u16*)C_p)[idx] = f2h(v);
                else         ((float*)C_p)[idx] = v;
            }
        }
    }
}

// ---------------- f32-A GEMM (steps 1,4: A = x, small N) ----------------
template <int BN, bool OUT_F16>
__global__ __launch_bounds__(256)
void gemm_xa(const float* __restrict__ A, const u16* __restrict__ B_g,
             void* __restrict__ C_p, int M, int N, int K) {
    constexpr int MI = (BN == 128) ? 4 : 2;
    constexpr int NJ = (BN == 32) ? 2 : 4;
    __shared__ u16 Ah[128][40], Bh[BN][40];
    const int t = threadIdx.x;
    const int wave = t >> 6, lane = t & 63;
    const int l15 = lane & 15, quad = lane >> 4;
    const int wm = (BN == 128) ? (wave >> 1) * 64 : wave * 32;
    const int wn = (BN == 128) ? (wave & 1) * 64 : 0;
    const int m0 = blockIdx.y * 128, n0 = blockIdx.x * BN;
    const int arow = t >> 1, acol = (t & 1) * 16;

    f32x4 acc[MI][NJ] = {};

    for (int k0 = 0; k0 < K; k0 += 32) {
        {
            const float* src = &A[(size_t)(m0 + arow) * K + k0 + acol];
            float4 w0 = ((const float4*)src)[0], w1 = ((const float4*)src)[1];
            float4 w2 = ((const float4*)src)[2], w3 = ((const float4*)src)[3];
            float v[16] = {w0.x, w0.y, w0.z, w0.w, w1.x, w1.y, w1.z, w1.w,
                           w2.x, w2.y, w2.z, w2.w, w3.x, w3.y, w3.z, w3.w};
            u16 hh[16];
#pragma unroll
            for (int e = 0; e < 16; ++e) hh[e] = f2h(v[e]);
            *(us8*)&Ah[arow][acol]     = *(const us8*)&hh[0];
            *(us8*)&Ah[arow][acol + 8] = *(const us8*)&hh[8];
        }
        if (t < BN * 2) {
            const int brow = t >> 1, bcol = (t & 1) * 16;
            size_t base = (size_t)(n0 + brow) * K + k0 + bcol;
            *(us8*)&Bh[brow][bcol]     = *(const us8*)&B_g[base];
            *(us8*)&Bh[brow][bcol + 8] = *(const us8*)&B_g[base + 8];
        }
        __syncthreads();

        h8 ah[MI], bh[NJ];
#pragma unroll
        for (int i = 0; i < MI; ++i)
            ah[i] = *(const h8*)&Ah[wm + i * 16 + l15][quad * 8];
#pragma unroll
        for (int j = 0; j < NJ; ++j)
            bh[j] = *(const h8*)&Bh[wn + j * 16 + l15][quad * 8];
#pragma unroll
        for (int i = 0; i < MI; ++i)
#pragma unroll
            for (int j = 0; j < NJ; ++j)
                acc[i][j] = __builtin_amdgcn_mfma_f32_16x16x32_f16(ah[i], bh[j], acc[i][j], 0, 0, 0);
        __syncthreads();
    }

#pragma unroll
    for (int j = 0; j < NJ; ++j) {
        const int col = n0 + wn + j * 16 + l15;
#pragma unroll
        for (int i = 0; i < MI; ++i) {
            const int rbase = m0 + wm + i * 16 + quad * 4;
#pragma unroll
            for (int r = 0; r < 4; ++r) {
                float v = acc[i][j][r];
                size_t idx = (size_t)(rbase + r) * N + col;
                if (OUT_F16) ((u16*)C_p)[idx] = f2h(v);
                else         ((float*)C_p)[idx] = v;
            }
        }
    }
}

// ---------------- kv: partial over n-segments ----------------
__global__ __launch_bounds__(256)
void kv_partial(const float* __restrict__ kmat, const float* __restrict__ kp,
                float* __restrict__ part) {
    const int b = blockIdx.y;
    const int seg = blockIdx.z;
    const int kk0 = blockIdx.x * 16;
    const int tid = threadIdx.x;
    const int d = tid & 63, s = tid >> 6;

    float acc[16] = {};
    const int nbeg = seg * 512;
    for (int n = nbeg + s; n < nbeg + 512; n += 4) {
        const float kval = kmat[((size_t)b * 4096 + n) * 64 + d];
        const float* kpr = &kp[(size_t)n * 256 + kk0];
#pragma unroll
        for (int j = 0; j < 16; ++j) acc[j] += kval * kpr[j];
    }
    __shared__ float sm[16][4][64];
#pragma unroll
    for (int j = 0; j < 16; ++j) sm[j][s][d] = acc[j];
    __syncthreads();
    for (int o = tid; o < 16 * 64; o += 256) {
        const int j = o >> 6, dd = o & 63;
        part[(((size_t)seg * 4 + b) * 256 + kk0 + j) * 64 + dd] =
            sm[j][0][dd] + sm[j][1][dd] + sm[j][2][dd] + sm[j][3][dd];
    }
}

// reduce 8 segments; emit f16 KV ([b][k][d]) and KV^T ([b][d][k])
__global__ __launch_bounds__(256)
void kv_reduce_cvt(const float* __restrict__ part,
                   u16* __restrict__ kvh, u16* __restrict__ kvTh) {
    const int i = blockIdx.x * 256 + threadIdx.x;  // 0..65535
    float s = 0.f;
#pragma unroll
    for (int seg = 0; seg < 8; ++seg) s += part[(size_t)seg * 65536 + i];
    u16 hh = f2h(s);
    kvh[i] = hh;
    const int b = i >> 14, k = (i >> 6) & 255, d = i & 63;
    kvTh[((size_t)b * 64 + d) * 256 + k] = hh;
}

// ---------------- fused attention v5: f16, LDS-staged KV chunks ----------
// Block: 128 queries x one (b,h); 4 waves x 32 queries. 4 chunks of 64 keys.
// exp(s-4): uniform shift cancels in normalization, keeps P in f16 range.
// LDS 34 KB -> 4 blocks/CU.
__global__ __launch_bounds__(256)
void attn_fused(const u16* __restrict__ qh,
                const u16* __restrict__ kvh, const u16* __restrict__ kvTh,
                u16* __restrict__ ath) {
    __shared__ u16 Kh_s[64][72];                 // K chunk  [k_loc][d]
    __shared__ u16 Vh_s[64][72];                 // V^T chunk [d][k_loc]
    __shared__ u16 Ps[128 * 64];                 // P chunk, XOR-swizzled
    const int b = blockIdx.z, h = blockIdx.y;
    const int t = threadIdx.x, wave = t >> 6, lane = t & 63;
    const int l15 = lane & 15, quad = lane >> 4;
    const int nblk = blockIdx.x * 128;
    const int nwav = wave * 32;
    char* Pb = (char*)Ps;

    // Q fragments (f16, direct from global)
    h8 Qf[2][2];
#pragma unroll
    for (int nt = 0; nt < 2; ++nt) {
        size_t qoff = ((size_t)(b * 4096 + nblk + nwav + nt * 16 + l15)) * 1024
                      + h * 64 + quad * 8;
#pragma unroll
        for (int c = 0; c < 2; ++c)
            Qf[nt][c] = *(const h8*)&qh[qoff + c * 32];
    }

    f32x4 O[2][4] = {};
    float rsum[2] = {0.f, 0.f};

    const int srow = t >> 3;            // 0..31, staging row
    const int scol = (t & 7) * 8;       // u16 col (16B chunk)
    const size_t kb = (size_t)b * 16384;

    for (int kc = 0; kc < 4; ++kc) {
        // ---- cooperative stage: K chunk + V^T chunk -> LDS
        {
            us8 s0 = *(const us8*)&kvh [kb + (size_t)(kc * 64 + srow     ) * 64 + scol];
            us8 s1 = *(const us8*)&kvh [kb + (size_t)(kc * 64 + srow + 32) * 64 + scol];
            us8 s4 = *(const us8*)&kvTh[kb + (size_t)(srow     ) * 256 + kc * 64 + scol];
            us8 s5 = *(const us8*)&kvTh[kb + (size_t)(srow + 32) * 256 + kc * 64 + scol];
            *(us8*)&Kh_s[srow     ][scol] = s0;
            *(us8*)&Kh_s[srow + 32][scol] = s1;
            *(us8*)&Vh_s[srow     ][scol] = s4;
            *(us8*)&Vh_s[srow + 32][scol] = s5;
        }
        __syncthreads();

        // ---- scores for this 64-key chunk (K from LDS)
        f32x4 S[2][4] = {};
#pragma unroll
        for (int ktl = 0; ktl < 4; ++ktl) {
            const int krl = ktl * 16 + l15;      // key row within chunk
#pragma unroll
            for (int c = 0; c < 2; ++c) {
                h8 Kf = *(const h8*)&Kh_s[krl][c * 32 + quad * 8];
#pragma unroll
                for (int nt = 0; nt < 2; ++nt)
                    S[nt][ktl] = __builtin_amdgcn_mfma_f32_16x16x32_f16(Kf, Qf[nt][c], S[nt][ktl], 0, 0, 0);
            }
        }
        // ---- exp(s/8 - 4): shift cancels in normalization; f16 P to LDS
        // (wave-private rows; swizzled byte addressing, same XOR both sides)
#pragma unroll
        for (int nt = 0; nt < 2; ++nt) {
            const int nrel = nwav + nt * 16 + l15;
#pragma unroll
            for (int ktl = 0; ktl < 4; ++ktl) {
                u16 pw[4];
#pragma unroll
                for (int r = 0; r < 4; ++r) {
                    float p = __expf(S[nt][ktl][r] * 0.125f - 4.0f);
                    rsum[nt] += p;
                    pw[r] = f2h(p);
                }
                *(us4*)(Pb + ((nrel * 128 + ktl * 32 + quad * 8) ^ ((nrel & 7) << 4)))
                    = *(const us4*)pw;
            }
        }

        // ---- PV for this chunk (V^T from LDS)
#pragma unroll
        for (int c = 0; c < 2; ++c) {
            h8 pf[2];
#pragma unroll
            for (int nt = 0; nt < 2; ++nt) {
                const int nrel = nwav + nt * 16 + l15;
                pf[nt] = *(const h8*)(Pb + ((nrel * 128 + c * 64 + quad * 16) ^ ((nrel & 7) << 4)));
            }
#pragma unroll
            for (int dt = 0; dt < 4; ++dt) {
                const int drow = dt * 16 + l15;
                h8 th = *(const h8*)&Vh_s[drow][c * 32 + quad * 8];
#pragma unroll
                for (int nt = 0; nt < 2; ++nt)
                    O[nt][dt] = __builtin_amdgcn_mfma_f32_16x16x32_f16(pf[nt], th, O[nt][dt], 0, 0, 0);
            }
        }
        __syncthreads();   // protect K/V LDS from next chunk's staging
    }

    // full softmax denominators (per query n = nwav+nt*16+l15)
    float inv[2];
#pragma unroll
    for (int nt = 0; nt < 2; ++nt) {
        float s = rsum[nt];
        s += __shfl_xor(s, 16, 64);
        s += __shfl_xor(s, 32, 64);
        inv[nt] = 1.f / s;
    }

    // C: col = l15 -> d, row = quad*4+r -> query. Fetch that query's inv via
    // shfl(width=16): source lane has l15 == quad*4+r, same quad group.
#pragma unroll
    for (int nt = 0; nt < 2; ++nt)
#pragma unroll
        for (int dt = 0; dt < 4; ++dt) {
            const int dcol = dt * 16 + l15;
#pragma unroll
            for (int r = 0; r < 4; ++r) {
                const float qinv = __shfl(inv[nt], quad * 4 + r, 16);
                const int query = nblk + nwav + nt * 16 + quad * 4 + r;
                float v = O[nt][dt][r] * qinv;
                size_t idx = (size_t)(b * 4096 + query) * 1024 + h * 64 + dcol;
                ath[idx] = f2h(v);
            }
        }
}

extern "C" void kernel_launch(void* const* d_in, const int* in_sizes, int n_in,
                              void* d_out, int out_size, void* d_ws, size_t ws_size,
                              hipStream_t stream) {
    const float* x  = (const float*)d_in[0];
    const float* qU = (const float*)d_in[1];
    const float* qV = (const float*)d_in[2];
    const float* qW = (const float*)d_in[3];
    const float* qb = (const float*)d_in[4];
    const float* kW = (const float*)d_in[5];
    const float* kp = (const float*)d_in[6];
    const float* oW = (const float*)d_in[7];
    const float* ob = (const float*)d_in[8];
    float* out = (float*)d_out;

    const int M = 16384;
    u16* W = (u16*)d_ws;
    u16* qUh = W;  W += 32768;
    u16* qVh = W;  W += 16384;
    u16* qWh = W;  W += 524288;
    u16* kWh = W;  W += 65536;
    u16* oWh = W;  W += 1048576;
    u16* t1h = W;  W += 524288;
    u16* t2h = W;  W += 8388608;     // 16 MB region
    u16* qhb = W;  W += 16777216;
    float* km  = (float*)W;  W += 2097152;     // 1048576 f32 (4 MB)
    u16* kvh  = W;  W += 65536;
    u16* kvTh = W;  W += 65536;
    u16* ath = qhb;                            // in-place over q buffer
    float* part = (float*)t2h;                 // 2 MB; t2 dead after step 3

    const dim3 blk(256);
    // 0) convert weights to f16
    cvt_w<<<dim3(32),   blk, 0, stream>>>(qU, qUh, 8192);
    cvt_w<<<dim3(16),   blk, 0, stream>>>(qV, qVh, 4096);
    cvt_w<<<dim3(512),  blk, 0, stream>>>(qW, qWh, 131072);
    cvt_w<<<dim3(64),   blk, 0, stream>>>(kW, kWh, 16384);
    cvt_w<<<dim3(1024), blk, 0, stream>>>(oW, oWh, 262144);
    // 1) t1 = x @ qU^T            (N=32, K=1024), f16 out
    gemm_xa<32, true><<<dim3(1, 128), blk, 0, stream>>>(
        x, qUh, t1h, M, 32, 1024);
    // 2) t2 = t1 @ qV^T           (N=512, K=32), f16 out
    gemm_ps<false, true><<<dim3(4, 128), blk, 0, stream>>>(
        t1h, qVh, nullptr, t2h, M, 512, 32);
    // 3) q = t2 @ qW^T + qb       (N=1024, K=512), f16 out
    gemm_ps<true, true><<<dim3(8, 128), blk, 0, stream>>>(
        t2h, qWh, qb, qhb, M, 1024, 512);
    // 4) km = x @ kW^T            (N=64, K=1024), f32 out
    gemm_xa<64, false><<<dim3(1, 128), blk, 0, stream>>>(
        x, kWh, km, M, 64, 1024);
    // 5) kv partial + reduce/convert (+ transpose)
    kv_partial<<<dim3(16, 4, 8), blk, 0, stream>>>(km, kp, part);
    kv_reduce_cvt<<<dim3(256), blk, 0, stream>>>(part, kvh, kvTh);
    // 6) fused attention (in-place over q buffer)
    attn_fused<<<dim3(32, 16, 4), blk, 0, stream>>>(qhb, kvh, kvTh, ath);
    // 7) out = at @ oW^T + ob     (N=1024, K=1024), f32 out
    gemm_ps<true, false><<<dim3(8, 128), blk, 0, stream>>>(
        ath, oWh, ob, out, M, 1024, 1024);
}

// Round 4
// 341.837 us; speedup vs baseline: 1.7845x; 1.1030x over previous
//
#include <hip/hip_runtime.h>

// LinformerSelfAttention  B=4 N=4096 E=1024 H=16 D=64 K=256 RANK=32
// f32 I/O.
// R8: attn KV chunks staged in LDS -> -90us (L2 same-line hotspot fixed).
// R9: single-f16 operands everywhere (-143us), XCD swizzle in gemm_ps.
// R10: algebra: Wc = qW@qV precomputed (f32 accum) -> q = (x@qU^T)@Wc^T,
//      eliminating the K=512 GEMM entirely; steps 1&4 fused into one
//      x-pass (B = [qU;kW], 96 cols) halving x reads.

typedef unsigned short u16;
typedef _Float16 f16;
typedef __attribute__((ext_vector_type(8))) _Float16 h8;        // 8 f16 (4 VGPR)
typedef __attribute__((ext_vector_type(4))) float f32x4;
typedef __attribute__((ext_vector_type(8))) unsigned short us8;
typedef __attribute__((ext_vector_type(4))) unsigned short us4;

__device__ __forceinline__ u16 f2h(float x) {
    f16 h = (f16)x;
    union { f16 hf; u16 u; } c; c.hf = h; return c.u;
}
__device__ __forceinline__ void async16(const void* g, void* l) {
    __builtin_amdgcn_global_load_lds(
        (const __attribute__((address_space(1))) void*)g,
        (__attribute__((address_space(3))) void*)l, 16, 0, 0);
}

// ---------------- weight converter: f32 -> f16 ----------------
__global__ __launch_bounds__(256)
void cvt_w(const float* __restrict__ src, u16* __restrict__ h, int n4) {
    int i = blockIdx.x * 256 + threadIdx.x;
    if (i >= n4) return;
    float4 v = ((const float4*)src)[i];
    u16 hh[4] = {f2h(v.x), f2h(v.y), f2h(v.z), f2h(v.w)};
    ((us4*)h)[i] = *(const us4*)hh;
}

// ---------------- Wc = qW @ qV  (1024x512 @ 512x32 -> 1024x32, f16 out) ---
// f32 accumulate; qV chunk staged in LDS. Grid: 32 blocks x 256 thr.
__global__ __launch_bounds__(256)
void wc_compute(const float* __restrict__ qW, const float* __restrict__ qV,
                u16* __restrict__ Wc) {
    __shared__ float Vs[128][32];
    const int t = threadIdx.x;
    const int nl = t >> 3;           // 0..31 local n-row
    const int rg = t & 7;            // r-group: r = rg*4 + rr
    const int n0 = blockIdx.x * 32;
    float acc[4] = {0.f, 0.f, 0.f, 0.f};
    for (int e0 = 0; e0 < 512; e0 += 128) {
#pragma unroll
        for (int u = 0; u < 16; ++u) {
            int idx = u * 256 + t;           // 0..4095
            int ee = idx >> 5, rr = idx & 31;
            Vs[ee][rr] = qV[(size_t)(e0 + ee) * 32 + rr];
        }
        __syncthreads();
        for (int e = 0; e < 128; ++e) {
            float w = qW[(size_t)(n0 + nl) * 512 + e0 + e];
#pragma unroll
            for (int rr = 0; rr < 4; ++rr)
                acc[rr] += w * Vs[e][rg * 4 + rr];
        }
        __syncthreads();
    }
#pragma unroll
    for (int rr = 0; rr < 4; ++rr)
        Wc[(size_t)(n0 + nl) * 32 + rg * 4 + rr] = f2h(acc[rr]);
}

// ---------------- f16 GEMM, async LDS staging ----------------
// C[m,n] = sum_k A[m,k]*B[n,k] (+bias[n]).  BM=BN=128, BK=32.
// XCD-aware swizzle: requires gridDim.x*gridDim.y % 8 == 0.
template <bool HAS_BIAS, bool OUT_F16>
__global__ __launch_bounds__(256)
void gemm_ps(const u16* __restrict__ A_g, const u16* __restrict__ B_g,
             const float* __restrict__ bias, void* __restrict__ C_p,
             int M, int N, int K) {
    __shared__ u16 LA[128 * 32], LB[128 * 32];
    const int t = threadIdx.x;
    const int wave = t >> 6, lane = t & 63;
    const int l15 = lane & 15, quad = lane >> 4;
    const int wm = (wave >> 1) * 64, wn = (wave & 1) * 64;
    const int gx = gridDim.x;
    const int nwg = gx * gridDim.y;
    const int flat = blockIdx.y * gx + blockIdx.x;
    const int cpx = nwg >> 3;
    const int swz = (flat & 7) * cpx + (flat >> 3);
    const int m0 = (swz / gx) * 128, n0 = (swz % gx) * 128;
    const int rl = lane >> 2, c4 = lane & 3;   // staging: row-in-16, 16B chunk

    f32x4 acc[4][4] = {};

    for (int k0 = 0; k0 < K; k0 += 32) {
#pragma unroll
        for (int j = 0; j < 2; ++j) {
            const int rloc = (wave * 2 + j) * 16 + rl;
            const size_t ga = (size_t)(m0 + rloc) * K + k0 + c4 * 8;
            const size_t gb = (size_t)(n0 + rloc) * K + k0 + c4 * 8;
            const int lo = (wave * 2 + j) * 512;   // u16 offset of this 1KB region
            async16(&A_g[ga], &LA[lo]);
            async16(&B_g[gb], &LB[lo]);
        }
        __syncthreads();

        h8 ah[4], bh[4];
#pragma unroll
        for (int i = 0; i < 4; ++i) {
            ah[i] = *(const h8*)&LA[(wm + i * 16 + l15) * 32 + quad * 8];
            bh[i] = *(const h8*)&LB[(wn + i * 16 + l15) * 32 + quad * 8];
        }
#pragma unroll
        for (int i = 0; i < 4; ++i)
#pragma unroll
            for (int j = 0; j < 4; ++j)
                acc[i][j] = __builtin_amdgcn_mfma_f32_16x16x32_f16(ah[i], bh[j], acc[i][j], 0, 0, 0);
        __syncthreads();
    }

    // C/D layout: col = lane&15 (B row), row = quad*4 + reg (A row)
#pragma unroll
    for (int j = 0; j < 4; ++j) {
        const int col = n0 + wn + j * 16 + l15;
        const float badd = HAS_BIAS ? bias[col] : 0.f;
#pragma unroll
        for (int i = 0; i < 4; ++i) {
            const int rbase = m0 + wm + i * 16 + quad * 4;
#pragma unroll
            for (int r = 0; r < 4; ++r) {
                float v = acc[i][j][r] + badd;
                size_t idx = (size_t)(rbase + r) * N + col;
                if (OUT_F16) ((u16*)C_p)[idx] = f2h(v);
                else         ((float*)C_p)[idx] = v;
            }
        }
    }
}

// ---------------- fused x-projection: t1 = x@qU^T (f16), km = x@kW^T (f32)
// B_g = concat f16 [qU(32 rows); kW(64 rows)] = 96 x 1024, row-major.
// BM=64 -> grid (1, 256) = full chip; reads x exactly once.
__global__ __launch_bounds__(256)
void gemm_x96(const float* __restrict__ A, const u16* __restrict__ B_g,
              u16* __restrict__ t1, float* __restrict__ km, int K) {
    __shared__ u16 Ah[64][40], Bh[96][40];
    const int t = threadIdx.x;
    const int wave = t >> 6, lane = t & 63;
    const int l15 = lane & 15, quad = lane >> 4;
    const int wm = wave * 16;              // each wave: 16 rows x 96 cols
    const int m0 = blockIdx.y * 64;
    const int arow = t >> 2, acol = (t & 3) * 8;

    f32x4 acc[6] = {};

    for (int k0 = 0; k0 < K; k0 += 32) {
        {   // stage A (f32 -> f16), 64 x 32
            const float* src = &A[(size_t)(m0 + arow) * K + k0 + acol];
            float4 w0 = ((const float4*)src)[0], w1 = ((const float4*)src)[1];
            float v[8] = {w0.x, w0.y, w0.z, w0.w, w1.x, w1.y, w1.z, w1.w};
            u16 hh[8];
#pragma unroll
            for (int e = 0; e < 8; ++e) hh[e] = f2h(v[e]);
            *(us8*)&Ah[arow][acol] = *(const us8*)&hh[0];
        }
        if (t < 192) {  // stage B 96 x 32 (f16 from global)
            const int brow = t >> 1, bcol = (t & 1) * 16;
            size_t base = (size_t)brow * K + k0 + bcol;
            *(us8*)&Bh[brow][bcol]     = *(const us8*)&B_g[base];
            *(us8*)&Bh[brow][bcol + 8] = *(const us8*)&B_g[base + 8];
        }
        __syncthreads();

        h8 ah = *(const h8*)&Ah[wm + l15][quad * 8];
        h8 bh[6];
#pragma unroll
        for (int j = 0; j < 6; ++j)
            bh[j] = *(const h8*)&Bh[j * 16 + l15][quad * 8];
#pragma unroll
        for (int j = 0; j < 6; ++j)
            acc[j] = __builtin_amdgcn_mfma_f32_16x16x32_f16(ah, bh[j], acc[j], 0, 0, 0);
        __syncthreads();
    }

    // cols 0..31 -> t1 (f16, N=32); cols 32..95 -> km (f32, N=64)
#pragma unroll
    for (int j = 0; j < 6; ++j) {
        const int col96 = j * 16 + l15;
        const int rbase = m0 + wm + quad * 4;
#pragma unroll
        for (int r = 0; r < 4; ++r) {
            float v = acc[j][r];
            const int row = rbase + r;
            if (col96 < 32) t1[(size_t)row * 32 + col96] = f2h(v);
            else            km[(size_t)row * 64 + (col96 - 32)] = v;
        }
    }
}

// ---------------- kv: partial over n-segments ----------------
__global__ __launch_bounds__(256)
void kv_partial(const float* __restrict__ kmat, const float* __restrict__ kp,
                float* __restrict__ part) {
    const int b = blockIdx.y;
    const int seg = blockIdx.z;
    const int kk0 = blockIdx.x * 16;
    const int tid = threadIdx.x;
    const int d = tid & 63, s = tid >> 6;

    float acc[16] = {};
    const int nbeg = seg * 512;
    for (int n = nbeg + s; n < nbeg + 512; n += 4) {
        const float kval = kmat[((size_t)b * 4096 + n) * 64 + d];
        const float* kpr = &kp[(size_t)n * 256 + kk0];
#pragma unroll
        for (int j = 0; j < 16; ++j) acc[j] += kval * kpr[j];
    }
    __shared__ float sm[16][4][64];
#pragma unroll
    for (int j = 0; j < 16; ++j) sm[j][s][d] = acc[j];
    __syncthreads();
    for (int o = tid; o < 16 * 64; o += 256) {
        const int j = o >> 6, dd = o & 63;
        part[(((size_t)seg * 4 + b) * 256 + kk0 + j) * 64 + dd] =
            sm[j][0][dd] + sm[j][1][dd] + sm[j][2][dd] + sm[j][3][dd];
    }
}

// reduce 8 segments; emit f16 KV ([b][k][d]) and KV^T ([b][d][k])
__global__ __launch_bounds__(256)
void kv_reduce_cvt(const float* __restrict__ part,
                   u16* __restrict__ kvh, u16* __restrict__ kvTh) {
    const int i = blockIdx.x * 256 + threadIdx.x;  // 0..65535
    float s = 0.f;
#pragma unroll
    for (int seg = 0; seg < 8; ++seg) s += part[(size_t)seg * 65536 + i];
    u16 hh = f2h(s);
    kvh[i] = hh;
    const int b = i >> 14, k = (i >> 6) & 255, d = i & 63;
    kvTh[((size_t)b * 64 + d) * 256 + k] = hh;
}

// ---------------- fused attention v5: f16, LDS-staged KV chunks ----------
__global__ __launch_bounds__(256)
void attn_fused(const u16* __restrict__ qh,
                const u16* __restrict__ kvh, const u16* __restrict__ kvTh,
                u16* __restrict__ ath) {
    __shared__ u16 Kh_s[64][72];                 // K chunk  [k_loc][d]
    __shared__ u16 Vh_s[64][72];                 // V^T chunk [d][k_loc]
    __shared__ u16 Ps[128 * 64];                 // P chunk, XOR-swizzled
    const int b = blockIdx.z, h = blockIdx.y;
    const int t = threadIdx.x, wave = t >> 6, lane = t & 63;
    const int l15 = lane & 15, quad = lane >> 4;
    const int nblk = blockIdx.x * 128;
    const int nwav = wave * 32;
    char* Pb = (char*)Ps;

    // Q fragments (f16, direct from global)
    h8 Qf[2][2];
#pragma unroll
    for (int nt = 0; nt < 2; ++nt) {
        size_t qoff = ((size_t)(b * 4096 + nblk + nwav + nt * 16 + l15)) * 1024
                      + h * 64 + quad * 8;
#pragma unroll
        for (int c = 0; c < 2; ++c)
            Qf[nt][c] = *(const h8*)&qh[qoff + c * 32];
    }

    f32x4 O[2][4] = {};
    float rsum[2] = {0.f, 0.f};

    const int srow = t >> 3;            // 0..31, staging row
    const int scol = (t & 7) * 8;       // u16 col (16B chunk)
    const size_t kb = (size_t)b * 16384;

    for (int kc = 0; kc < 4; ++kc) {
        // ---- cooperative stage: K chunk + V^T chunk -> LDS
        {
            us8 s0 = *(const us8*)&kvh [kb + (size_t)(kc * 64 + srow     ) * 64 + scol];
            us8 s1 = *(const us8*)&kvh [kb + (size_t)(kc * 64 + srow + 32) * 64 + scol];
            us8 s4 = *(const us8*)&kvTh[kb + (size_t)(srow     ) * 256 + kc * 64 + scol];
            us8 s5 = *(const us8*)&kvTh[kb + (size_t)(srow + 32) * 256 + kc * 64 + scol];
            *(us8*)&Kh_s[srow     ][scol] = s0;
            *(us8*)&Kh_s[srow + 32][scol] = s1;
            *(us8*)&Vh_s[srow     ][scol] = s4;
            *(us8*)&Vh_s[srow + 32][scol] = s5;
        }
        __syncthreads();

        // ---- scores for this 64-key chunk (K from LDS)
        f32x4 S[2][4] = {};
#pragma unroll
        for (int ktl = 0; ktl < 4; ++ktl) {
            const int krl = ktl * 16 + l15;      // key row within chunk
#pragma unroll
            for (int c = 0; c < 2; ++c) {
                h8 Kf = *(const h8*)&Kh_s[krl][c * 32 + quad * 8];
#pragma unroll
                for (int nt = 0; nt < 2; ++nt)
                    S[nt][ktl] = __builtin_amdgcn_mfma_f32_16x16x32_f16(Kf, Qf[nt][c], S[nt][ktl], 0, 0, 0);
            }
        }
        // ---- exp(s/8 - 4): shift cancels in normalization; f16 P to LDS
#pragma unroll
        for (int nt = 0; nt < 2; ++nt) {
            const int nrel = nwav + nt * 16 + l15;
#pragma unroll
            for (int ktl = 0; ktl < 4; ++ktl) {
                u16 pw[4];
#pragma unroll
                for (int r = 0; r < 4; ++r) {
                    float p = __expf(S[nt][ktl][r] * 0.125f - 4.0f);
                    rsum[nt] += p;
                    pw[r] = f2h(p);
                }
                *(us4*)(Pb + ((nrel * 128 + ktl * 32 + quad * 8) ^ ((nrel & 7) << 4)))
                    = *(const us4*)pw;
            }
        }

        // ---- PV for this chunk (V^T from LDS)
#pragma unroll
        for (int c = 0; c < 2; ++c) {
            h8 pf[2];
#pragma unroll
            for (int nt = 0; nt < 2; ++nt) {
                const int nrel = nwav + nt * 16 + l15;
                pf[nt] = *(const h8*)(Pb + ((nrel * 128 + c * 64 + quad * 16) ^ ((nrel & 7) << 4)));
            }
#pragma unroll
            for (int dt = 0; dt < 4; ++dt) {
                const int drow = dt * 16 + l15;
                h8 th = *(const h8*)&Vh_s[drow][c * 32 + quad * 8];
#pragma unroll
                for (int nt = 0; nt < 2; ++nt)
                    O[nt][dt] = __builtin_amdgcn_mfma_f32_16x16x32_f16(pf[nt], th, O[nt][dt], 0, 0, 0);
            }
        }
        __syncthreads();   // protect K/V LDS from next chunk's staging
    }

    // full softmax denominators (per query n = nwav+nt*16+l15)
    float inv[2];
#pragma unroll
    for (int nt = 0; nt < 2; ++nt) {
        float s = rsum[nt];
        s += __shfl_xor(s, 16, 64);
        s += __shfl_xor(s, 32, 64);
        inv[nt] = 1.f / s;
    }

    // C: col = l15 -> d, row = quad*4+r -> query.
#pragma unroll
    for (int nt = 0; nt < 2; ++nt)
#pragma unroll
        for (int dt = 0; dt < 4; ++dt) {
            const int dcol = dt * 16 + l15;
#pragma unroll
            for (int r = 0; r < 4; ++r) {
                const float qinv = __shfl(inv[nt], quad * 4 + r, 16);
                const int query = nblk + nwav + nt * 16 + quad * 4 + r;
                float v = O[nt][dt][r] * qinv;
                size_t idx = (size_t)(b * 4096 + query) * 1024 + h * 64 + dcol;
                ath[idx] = f2h(v);
            }
        }
}

extern "C" void kernel_launch(void* const* d_in, const int* in_sizes, int n_in,
                              void* d_out, int out_size, void* d_ws, size_t ws_size,
                              hipStream_t stream) {
    const float* x  = (const float*)d_in[0];
    const float* qU = (const float*)d_in[1];
    const float* qV = (const float*)d_in[2];
    const float* qW = (const float*)d_in[3];
    const float* qb = (const float*)d_in[4];
    const float* kW = (const float*)d_in[5];
    const float* kp = (const float*)d_in[6];
    const float* oW = (const float*)d_in[7];
    const float* ob = (const float*)d_in[8];
    float* out = (float*)d_out;

    const int M = 16384;
    u16* W = (u16*)d_ws;
    u16* bUK = W;  W += 98304;       // [qU(32); kW(64)] x 1024, f16
    u16* oWh = W;  W += 1048576;
    u16* WcH = W;  W += 32768;       // Wc = qW@qV, 1024 x 32, f16
    u16* t1h = W;  W += 524288;
    u16* qhb = W;  W += 16777216;
    float* km  = (float*)W;  W += 2097152;     // 16384 x 64 f32 (4 MB)
    float* part = (float*)W; W += 1048576;     // 8x4x256x64 f32 (2 MB)
    u16* kvh  = W;  W += 65536;
    u16* kvTh = W;  W += 65536;
    u16* ath = qhb;                            // in-place over q buffer

    const dim3 blk(256);
    // 0) weight prep
    cvt_w<<<dim3(32),   blk, 0, stream>>>(qU, bUK, 8192);
    cvt_w<<<dim3(64),   blk, 0, stream>>>(kW, bUK + 32768, 16384);
    cvt_w<<<dim3(1024), blk, 0, stream>>>(oW, oWh, 262144);
    wc_compute<<<dim3(32), blk, 0, stream>>>(qW, qV, WcH);
    // 1) single x pass: t1 = x @ qU^T (f16), km = x @ kW^T (f32)
    gemm_x96<<<dim3(1, 256), blk, 0, stream>>>(x, bUK, t1h, km, 1024);
    // 2) kv partial + reduce/convert (+ transpose)
    kv_partial<<<dim3(16, 4, 8), blk, 0, stream>>>(km, kp, part);
    kv_reduce_cvt<<<dim3(256), blk, 0, stream>>>(part, kvh, kvTh);
    // 3) q = t1 @ Wc^T + qb       (N=1024, K=32), f16 out
    gemm_ps<true, true><<<dim3(8, 128), blk, 0, stream>>>(
        t1h, WcH, qb, qhb, M, 1024, 32);
    // 4) fused attention (in-place over q buffer)
    attn_fused<<<dim3(32, 16, 4), blk, 0, stream>>>(qhb, kvh, kvTh, ath);
    // 5) out = at @ oW^T + ob     (N=1024, K=1024), f32 out
    gemm_ps<true, false><<<dim3(8, 128), blk, 0, stream>>>(
        ath, oWh, ob, out, M, 1024, 1024);
}

// Round 6
// 324.621 us; speedup vs baseline: 1.8792x; 1.0530x over previous
//
#include <hip/hip_runtime.h>

// LinformerSelfAttention  B=4 N=4096 E=1024 H=16 D=64 K=256 RANK=32
// f32 I/O.
// R8: attn KV chunks staged in LDS -> -90us (L2 same-line hotspot fixed).
// R9: single-f16 operands everywhere (-143us), XCD swizzle in gemm_ps.
// R10: Wc = qW@qV precompute kills the K=512 GEMM; steps 1&4 fused.
// R11: launch-count 10 -> 6 (prep merged; q-projection folded INTO
//      attn_fused via 8 MFMA + LDS overlay); FAILED: t1 row index was
//      missing the b*4096 batch offset.
// R12: fix the t1 batch offset (one line). No other changes.

typedef unsigned short u16;
typedef _Float16 f16;
typedef __attribute__((ext_vector_type(8))) _Float16 h8;        // 8 f16 (4 VGPR)
typedef __attribute__((ext_vector_type(4))) float f32x4;
typedef __attribute__((ext_vector_type(8))) unsigned short us8;
typedef __attribute__((ext_vector_type(4))) unsigned short us4;

__device__ __forceinline__ u16 f2h(float x) {
    f16 h = (f16)x;
    union { f16 hf; u16 u; } c; c.hf = h; return c.u;
}
__device__ __forceinline__ void async16(const void* g, void* l) {
    __builtin_amdgcn_global_load_lds(
        (const __attribute__((address_space(1))) void*)g,
        (__attribute__((address_space(3))) void*)l, 16, 0, 0);
}

// ---------------- prep: all weight conversion + Wc = qW@qV ----------------
// blocks [0,32): Wc    [32,64): qU->f16   [64,128): kW->f16   [128,1152): oW
__global__ __launch_bounds__(256)
void prep(const float* __restrict__ qU, const float* __restrict__ qV,
          const float* __restrict__ qW, const float* __restrict__ kW,
          const float* __restrict__ oW,
          u16* __restrict__ bUK, u16* __restrict__ oWh, u16* __restrict__ WcH) {
    __shared__ float Vs[128][32];
    const int bx = blockIdx.x, t = threadIdx.x;
    if (bx < 32) {
        // Wc = qW @ qV  (1024x512 @ 512x32), f32 accum, f16 out
        const int nl = t >> 3;           // 0..31 local n-row
        const int rg = t & 7;            // r-group: r = rg*4 + rr
        const int n0 = bx * 32;
        float acc[4] = {0.f, 0.f, 0.f, 0.f};
        for (int e0 = 0; e0 < 512; e0 += 128) {
#pragma unroll
            for (int u = 0; u < 16; ++u) {
                int idx = u * 256 + t;
                int ee = idx >> 5, rr = idx & 31;
                Vs[ee][rr] = qV[(size_t)(e0 + ee) * 32 + rr];
            }
            __syncthreads();
            for (int e = 0; e < 128; ++e) {
                float w = qW[(size_t)(n0 + nl) * 512 + e0 + e];
#pragma unroll
                for (int rr = 0; rr < 4; ++rr)
                    acc[rr] += w * Vs[e][rg * 4 + rr];
            }
            __syncthreads();
        }
#pragma unroll
        for (int rr = 0; rr < 4; ++rr)
            WcH[(size_t)(n0 + nl) * 32 + rg * 4 + rr] = f2h(acc[rr]);
    } else if (bx < 64) {
        int i = (bx - 32) * 256 + t;               // qU: 8192 float4
        float4 v = ((const float4*)qU)[i];
        u16 hh[4] = {f2h(v.x), f2h(v.y), f2h(v.z), f2h(v.w)};
        ((us4*)bUK)[i] = *(const us4*)hh;
    } else if (bx < 128) {
        int i = (bx - 64) * 256 + t;               // kW: 16384 float4
        float4 v = ((const float4*)kW)[i];
        u16 hh[4] = {f2h(v.x), f2h(v.y), f2h(v.z), f2h(v.w)};
        ((us4*)(bUK + 32768))[i] = *(const us4*)hh;
    } else {
        int i = (bx - 128) * 256 + t;              // oW: 262144 float4
        float4 v = ((const float4*)oW)[i];
        u16 hh[4] = {f2h(v.x), f2h(v.y), f2h(v.z), f2h(v.w)};
        ((us4*)oWh)[i] = *(const us4*)hh;
    }
}

// ---------------- f16 GEMM, async LDS staging ----------------
// C[m,n] = sum_k A[m,k]*B[n,k] (+bias[n]).  BM=BN=128, BK=32.
// XCD-aware swizzle: requires gridDim.x*gridDim.y % 8 == 0.
template <bool HAS_BIAS, bool OUT_F16>
__global__ __launch_bounds__(256)
void gemm_ps(const u16* __restrict__ A_g, const u16* __restrict__ B_g,
             const float* __restrict__ bias, void* __restrict__ C_p,
             int M, int N, int K) {
    __shared__ u16 LA[128 * 32], LB[128 * 32];
    const int t = threadIdx.x;
    const int wave = t >> 6, lane = t & 63;
    const int l15 = lane & 15, quad = lane >> 4;
    const int wm = (wave >> 1) * 64, wn = (wave & 1) * 64;
    const int gx = gridDim.x;
    const int nwg = gx * gridDim.y;
    const int flat = blockIdx.y * gx + blockIdx.x;
    const int cpx = nwg >> 3;
    const int swz = (flat & 7) * cpx + (flat >> 3);
    const int m0 = (swz / gx) * 128, n0 = (swz % gx) * 128;
    const int rl = lane >> 2, c4 = lane & 3;   // staging: row-in-16, 16B chunk

    f32x4 acc[4][4] = {};

    for (int k0 = 0; k0 < K; k0 += 32) {
#pragma unroll
        for (int j = 0; j < 2; ++j) {
            const int rloc = (wave * 2 + j) * 16 + rl;
            const size_t ga = (size_t)(m0 + rloc) * K + k0 + c4 * 8;
            const size_t gb = (size_t)(n0 + rloc) * K + k0 + c4 * 8;
            const int lo = (wave * 2 + j) * 512;   // u16 offset of this 1KB region
            async16(&A_g[ga], &LA[lo]);
            async16(&B_g[gb], &LB[lo]);
        }
        __syncthreads();

        h8 ah[4], bh[4];
#pragma unroll
        for (int i = 0; i < 4; ++i) {
            ah[i] = *(const h8*)&LA[(wm + i * 16 + l15) * 32 + quad * 8];
            bh[i] = *(const h8*)&LB[(wn + i * 16 + l15) * 32 + quad * 8];
        }
#pragma unroll
        for (int i = 0; i < 4; ++i)
#pragma unroll
            for (int j = 0; j < 4; ++j)
                acc[i][j] = __builtin_amdgcn_mfma_f32_16x16x32_f16(ah[i], bh[j], acc[i][j], 0, 0, 0);
        __syncthreads();
    }

    // C/D layout: col = lane&15 (B row), row = quad*4 + reg (A row)
#pragma unroll
    for (int j = 0; j < 4; ++j) {
        const int col = n0 + wn + j * 16 + l15;
        const float badd = HAS_BIAS ? bias[col] : 0.f;
#pragma unroll
        for (int i = 0; i < 4; ++i) {
            const int rbase = m0 + wm + i * 16 + quad * 4;
#pragma unroll
            for (int r = 0; r < 4; ++r) {
                float v = acc[i][j][r] + badd;
                size_t idx = (size_t)(rbase + r) * N + col;
                if (OUT_F16) ((u16*)C_p)[idx] = f2h(v);
                else         ((float*)C_p)[idx] = v;
            }
        }
    }
}

// ---------------- fused x-projection: t1 = x@qU^T (f16), km = x@kW^T (f32)
// B_g = concat f16 [qU(32 rows); kW(64 rows)] = 96 x 1024, row-major.
// BM=64 -> grid (1, 256) = full chip; reads x exactly once.
__global__ __launch_bounds__(256)
void gemm_x96(const float* __restrict__ A, const u16* __restrict__ B_g,
              u16* __restrict__ t1, float* __restrict__ km, int K) {
    __shared__ u16 Ah[64][40], Bh[96][40];
    const int t = threadIdx.x;
    const int wave = t >> 6, lane = t & 63;
    const int l15 = lane & 15, quad = lane >> 4;
    const int wm = wave * 16;              // each wave: 16 rows x 96 cols
    const int m0 = blockIdx.y * 64;
    const int arow = t >> 2, acol = (t & 3) * 8;

    f32x4 acc[6] = {};

    for (int k0 = 0; k0 < K; k0 += 32) {
        {   // stage A (f32 -> f16), 64 x 32
            const float* src = &A[(size_t)(m0 + arow) * K + k0 + acol];
            float4 w0 = ((const float4*)src)[0], w1 = ((const float4*)src)[1];
            float v[8] = {w0.x, w0.y, w0.z, w0.w, w1.x, w1.y, w1.z, w1.w};
            u16 hh[8];
#pragma unroll
            for (int e = 0; e < 8; ++e) hh[e] = f2h(v[e]);
            *(us8*)&Ah[arow][acol] = *(const us8*)&hh[0];
        }
        if (t < 192) {  // stage B 96 x 32 (f16 from global)
            const int brow = t >> 1, bcol = (t & 1) * 16;
            size_t base = (size_t)brow * K + k0 + bcol;
            *(us8*)&Bh[brow][bcol]     = *(const us8*)&B_g[base];
            *(us8*)&Bh[brow][bcol + 8] = *(const us8*)&B_g[base + 8];
        }
        __syncthreads();

        h8 ah = *(const h8*)&Ah[wm + l15][quad * 8];
        h8 bh[6];
#pragma unroll
        for (int j = 0; j < 6; ++j)
            bh[j] = *(const h8*)&Bh[j * 16 + l15][quad * 8];
#pragma unroll
        for (int j = 0; j < 6; ++j)
            acc[j] = __builtin_amdgcn_mfma_f32_16x16x32_f16(ah, bh[j], acc[j], 0, 0, 0);
        __syncthreads();
    }

    // cols 0..31 -> t1 (f16, N=32); cols 32..95 -> km (f32, N=64)
#pragma unroll
    for (int j = 0; j < 6; ++j) {
        const int col96 = j * 16 + l15;
        const int rbase = m0 + wm + quad * 4;
#pragma unroll
        for (int r = 0; r < 4; ++r) {
            float v = acc[j][r];
            const int row = rbase + r;
            if (col96 < 32) t1[(size_t)row * 32 + col96] = f2h(v);
            else            km[(size_t)row * 64 + (col96 - 32)] = v;
        }
    }
}

// ---------------- kv: partial over n-segments ----------------
__global__ __launch_bounds__(256)
void kv_partial(const float* __restrict__ kmat, const float* __restrict__ kp,
                float* __restrict__ part) {
    const int b = blockIdx.y;
    const int seg = blockIdx.z;
    const int kk0 = blockIdx.x * 16;
    const int tid = threadIdx.x;
    const int d = tid & 63, s = tid >> 6;

    float acc[16] = {};
    const int nbeg = seg * 512;
    for (int n = nbeg + s; n < nbeg + 512; n += 4) {
        const float kval = kmat[((size_t)b * 4096 + n) * 64 + d];
        const float* kpr = &kp[(size_t)n * 256 + kk0];
#pragma unroll
        for (int j = 0; j < 16; ++j) acc[j] += kval * kpr[j];
    }
    __shared__ float sm[16][4][64];
#pragma unroll
    for (int j = 0; j < 16; ++j) sm[j][s][d] = acc[j];
    __syncthreads();
    for (int o = tid; o < 16 * 64; o += 256) {
        const int j = o >> 6, dd = o & 63;
        part[(((size_t)seg * 4 + b) * 256 + kk0 + j) * 64 + dd] =
            sm[j][0][dd] + sm[j][1][dd] + sm[j][2][dd] + sm[j][3][dd];
    }
}

// reduce 8 segments; emit f16 KV ([b][k][d]) and KV^T ([b][d][k])
__global__ __launch_bounds__(256)
void kv_reduce_cvt(const float* __restrict__ part,
                   u16* __restrict__ kvh, u16* __restrict__ kvTh) {
    const int i = blockIdx.x * 256 + threadIdx.x;  // 0..65535
    float s = 0.f;
#pragma unroll
    for (int seg = 0; seg < 8; ++seg) s += part[(size_t)seg * 65536 + i];
    u16 hh = f2h(s);
    kvh[i] = hh;
    const int b = i >> 14, k = (i >> 6) & 255, d = i & 63;
    kvTh[((size_t)b * 64 + d) * 256 + k] = hh;
}

// ---------------- fused attention v6: q computed in-kernel --------------
// Block: 128 queries x one (b,h); 4 waves x 32 queries. 4 chunks of 64 keys.
// Phase 0: q = t1 @ Wc^T + qb via 8 MFMA/wave, staged through q_s (LDS),
//          Q fragments pulled to registers, then q_s region is DEAD and
//          overlaid by K/V/P (one barrier separates the lifetimes).
// LDS 34816 B -> 4 blocks/CU.
__global__ __launch_bounds__(256)
void attn_fused(const u16* __restrict__ t1, const u16* __restrict__ WcH,
                const float* __restrict__ qb,
                const u16* __restrict__ kvh, const u16* __restrict__ kvTh,
                u16* __restrict__ ath) {
    __shared__ __align__(16) char SMEM[34816];
    u16 (*q_s)[72]  = (u16(*)[72])SMEM;              // [128][72], phase 0 only
    u16 (*Kh_s)[72] = (u16(*)[72])SMEM;              // [64][72]
    u16 (*Vh_s)[72] = (u16(*)[72])(SMEM + 9216);     // [64][72]
    char* Pb        = SMEM + 18432;                  // 16384 B, XOR-swizzled

    const int b = blockIdx.z, h = blockIdx.y;
    const int t = threadIdx.x, wave = t >> 6, lane = t & 63;
    const int l15 = lane & 15, quad = lane >> 4;
    const int nblk = blockIdx.x * 128;
    const int nwav = wave * 32;

    // ---- phase 0: q-tile = t1 @ Wc^T + qb  (rows nwav..nwav+31 per wave)
    {
        h8 ta[2], wb[4];
#pragma unroll
        for (int nt = 0; nt < 2; ++nt)
            ta[nt] = *(const h8*)&t1[(size_t)(b * 4096 + nblk + nwav + nt * 16 + l15) * 32 + quad * 8];
#pragma unroll
        for (int j = 0; j < 4; ++j)
            wb[j] = *(const h8*)&WcH[(size_t)(h * 64 + j * 16 + l15) * 32 + quad * 8];
#pragma unroll
        for (int nt = 0; nt < 2; ++nt)
#pragma unroll
            for (int j = 0; j < 4; ++j) {
                f32x4 qa = {};
                qa = __builtin_amdgcn_mfma_f32_16x16x32_f16(ta[nt], wb[j], qa, 0, 0, 0);
                const float badd = qb[h * 64 + j * 16 + l15];
                // C layout: col=l15 -> Wc row (hd), row=quad*4+r -> query
#pragma unroll
                for (int r = 0; r < 4; ++r)
                    q_s[nwav + nt * 16 + quad * 4 + r][j * 16 + l15] = f2h(qa[r] + badd);
            }
    }
    // wave-private rows: fragments readable without barrier
    h8 Qf[2][2];
#pragma unroll
    for (int nt = 0; nt < 2; ++nt)
#pragma unroll
        for (int c = 0; c < 2; ++c)
            Qf[nt][c] = *(const h8*)&q_s[nwav + nt * 16 + l15][c * 32 + quad * 8];
    __syncthreads();   // q_s dead; K/V/P overlay becomes live

    f32x4 O[2][4] = {};
    float rsum[2] = {0.f, 0.f};

    const int srow = t >> 3;            // 0..31, staging row
    const int scol = (t & 7) * 8;       // u16 col (16B chunk)
    const size_t kb = (size_t)b * 16384;

    for (int kc = 0; kc < 4; ++kc) {
        // ---- cooperative stage: K chunk + V^T chunk -> LDS
        {
            us8 s0 = *(const us8*)&kvh [kb + (size_t)(kc * 64 + srow     ) * 64 + scol];
            us8 s1 = *(const us8*)&kvh [kb + (size_t)(kc * 64 + srow + 32) * 64 + scol];
            us8 s4 = *(const us8*)&kvTh[kb + (size_t)(srow     ) * 256 + kc * 64 + scol];
            us8 s5 = *(const us8*)&kvTh[kb + (size_t)(srow + 32) * 256 + kc * 64 + scol];
            *(us8*)&Kh_s[srow     ][scol] = s0;
            *(us8*)&Kh_s[srow + 32][scol] = s1;
            *(us8*)&Vh_s[srow     ][scol] = s4;
            *(us8*)&Vh_s[srow + 32][scol] = s5;
        }
        __syncthreads();

        // ---- scores for this 64-key chunk (K from LDS)
        f32x4 S[2][4] = {};
#pragma unroll
        for (int ktl = 0; ktl < 4; ++ktl) {
            const int krl = ktl * 16 + l15;      // key row within chunk
#pragma unroll
            for (int c = 0; c < 2; ++c) {
                h8 Kf = *(const h8*)&Kh_s[krl][c * 32 + quad * 8];
#pragma unroll
                for (int nt = 0; nt < 2; ++nt)
                    S[nt][ktl] = __builtin_amdgcn_mfma_f32_16x16x32_f16(Kf, Qf[nt][c], S[nt][ktl], 0, 0, 0);
            }
        }
        // ---- exp(s/8 - 4): shift cancels in normalization; f16 P to LDS
        // (wave-private rows; swizzled byte addressing, same XOR both sides)
#pragma unroll
        for (int nt = 0; nt < 2; ++nt) {
            const int nrel = nwav + nt * 16 + l15;
#pragma unroll
            for (int ktl = 0; ktl < 4; ++ktl) {
                u16 pw[4];
#pragma unroll
                for (int r = 0; r < 4; ++r) {
                    float p = __expf(S[nt][ktl][r] * 0.125f - 4.0f);
                    rsum[nt] += p;
                    pw[r] = f2h(p);
                }
                *(us4*)(Pb + ((nrel * 128 + ktl * 32 + quad * 8) ^ ((nrel & 7) << 4)))
                    = *(const us4*)pw;
            }
        }

        // ---- PV for this chunk (V^T from LDS)
#pragma unroll
        for (int c = 0; c < 2; ++c) {
            h8 pf[2];
#pragma unroll
            for (int nt = 0; nt < 2; ++nt) {
                const int nrel = nwav + nt * 16 + l15;
                pf[nt] = *(const h8*)(Pb + ((nrel * 128 + c * 64 + quad * 16) ^ ((nrel & 7) << 4)));
            }
#pragma unroll
            for (int dt = 0; dt < 4; ++dt) {
                const int drow = dt * 16 + l15;
                h8 th = *(const h8*)&Vh_s[drow][c * 32 + quad * 8];
#pragma unroll
                for (int nt = 0; nt < 2; ++nt)
                    O[nt][dt] = __builtin_amdgcn_mfma_f32_16x16x32_f16(pf[nt], th, O[nt][dt], 0, 0, 0);
            }
        }
        __syncthreads();   // protect K/V LDS from next chunk's staging
    }

    // full softmax denominators (per query n = nwav+nt*16+l15)
    float inv[2];
#pragma unroll
    for (int nt = 0; nt < 2; ++nt) {
        float s = rsum[nt];
        s += __shfl_xor(s, 16, 64);
        s += __shfl_xor(s, 32, 64);
        inv[nt] = 1.f / s;
    }

    // C: col = l15 -> d, row = quad*4+r -> query.
#pragma unroll
    for (int nt = 0; nt < 2; ++nt)
#pragma unroll
        for (int dt = 0; dt < 4; ++dt) {
            const int dcol = dt * 16 + l15;
#pragma unroll
            for (int r = 0; r < 4; ++r) {
                const float qinv = __shfl(inv[nt], quad * 4 + r, 16);
                const int query = nblk + nwav + nt * 16 + quad * 4 + r;
                float v = O[nt][dt][r] * qinv;
                size_t idx = (size_t)(b * 4096 + query) * 1024 + h * 64 + dcol;
                ath[idx] = f2h(v);
            }
        }
}

extern "C" void kernel_launch(void* const* d_in, const int* in_sizes, int n_in,
                              void* d_out, int out_size, void* d_ws, size_t ws_size,
                              hipStream_t stream) {
    const float* x  = (const float*)d_in[0];
    const float* qU = (const float*)d_in[1];
    const float* qV = (const float*)d_in[2];
    const float* qW = (const float*)d_in[3];
    const float* qb = (const float*)d_in[4];
    const float* kW = (const float*)d_in[5];
    const float* kp = (const float*)d_in[6];
    const float* oW = (const float*)d_in[7];
    const float* ob = (const float*)d_in[8];
    float* out = (float*)d_out;

    const int M = 16384;
    u16* W = (u16*)d_ws;
    u16* bUK = W;  W += 98304;       // [qU(32); kW(64)] x 1024, f16
    u16* oWh = W;  W += 1048576;
    u16* WcH = W;  W += 32768;       // Wc = qW@qV, 1024 x 32, f16
    u16* t1h = W;  W += 524288;
    u16* ath = W;  W += 16777216;    // at, 16384 x 1024 f16
    float* km  = (float*)W;  W += 2097152;     // 16384 x 64 f32 (4 MB)
    float* part = (float*)W; W += 1048576;     // 8x4x256x64 f32 (2 MB)
    u16* kvh  = W;  W += 65536;
    u16* kvTh = W;  W += 65536;

    const dim3 blk(256);
    // 0) all weight prep (conversions + Wc) in one launch
    prep<<<dim3(1152), blk, 0, stream>>>(qU, qV, qW, kW, oW, bUK, oWh, WcH);
    // 1) single x pass: t1 = x @ qU^T (f16), km = x @ kW^T (f32)
    gemm_x96<<<dim3(1, 256), blk, 0, stream>>>(x, bUK, t1h, km, 1024);
    // 2) kv partial + reduce/convert (+ transpose)
    kv_partial<<<dim3(16, 4, 8), blk, 0, stream>>>(km, kp, part);
    kv_reduce_cvt<<<dim3(256), blk, 0, stream>>>(part, kvh, kvTh);
    // 3) fused attention (q computed in-kernel from t1/Wc/qb)
    attn_fused<<<dim3(32, 16, 4), blk, 0, stream>>>(t1h, WcH, qb, kvh, kvTh, ath);
    // 4) out = at @ oW^T + ob     (N=1024, K=1024), f32 out
    gemm_ps<true, false><<<dim3(8, 128), blk, 0, stream>>>(
        ath, oWh, ob, out, M, 1024, 1024);
}